// Round 4
// baseline (1078.552 us; speedup 1.0000x reference)
//
#include <hip/hip_runtime.h>
#include <stdint.h>

// MultiHeadSlotAttention on MI355X (gfx950).
// dots = (SCALE*q@Wk_h^T).x_ln + SCALE*q.bk ; updates = ((sum_j p*x_ln + EPS*xsum)/S)@Wv + bv
// K/V never materialized. LN(x) precomputed ONCE to bf16 (row-major + transposed) when ws
// allows; per iteration: MFMA attention pass + wide reduce (s3a) + skinny-GEMM update (s3b).

#define NSLOT 8
#define R32   32
#define SEQN  4096

constexpr float EPSA    = 1e-8f;
constexpr float LNEPS   = 1e-5f;
constexpr float SCALE_F = 0.125f;

typedef short s16x8 __attribute__((ext_vector_type(8)));
typedef short s16x4 __attribute__((ext_vector_type(4)));
typedef float f32x4 __attribute__((ext_vector_type(4)));

__device__ __forceinline__ short f2bf(float f) {
  uint32_t u = __float_as_uint(f);
  uint32_t r = (u + 0x7FFFu + ((u >> 16) & 1u)) >> 16;
  return (short)r;
}
__device__ __forceinline__ float bf2f(short s) {
  return __uint_as_float(((uint32_t)(uint16_t)s) << 16);
}
// dot of bf16 weight row (global) with f32 vector (LDS, wave-uniform -> broadcast reads)
__device__ __forceinline__ float dotw(const short* __restrict__ w, const float* __restrict__ x, int n) {
  float acc = 0.f;
  #pragma unroll 4
  for (int i = 0; i < n; i += 8) {
    s16x8 wv = *(const s16x8*)(w + i);
    f32x4 xa = *(const f32x4*)(x + i);
    f32x4 xb = *(const f32x4*)(x + i + 4);
    acc += bf2f(wv[0])*xa[0]; acc += bf2f(wv[1])*xa[1];
    acc += bf2f(wv[2])*xa[2]; acc += bf2f(wv[3])*xa[3];
    acc += bf2f(wv[4])*xb[0]; acc += bf2f(wv[5])*xb[1];
    acc += bf2f(wv[6])*xb[2]; acc += bf2f(wv[7])*xb[3];
  }
  return acc;
}

// ---------------------------------------------------------------------------
__global__ __launch_bounds__(256) void w_cast(
    const float* __restrict__ W_ih, const float* __restrict__ W_hh,
    const float* __restrict__ Wk,
    short* __restrict__ WihB, short* __restrict__ WhhB, short* __restrict__ WkB)
{
  int idx4 = blockIdx.x*256 + threadIdx.x;
  const float* src; short* dst; int off;
  if (idx4 < 49152)        { src = W_ih; dst = WihB; off = idx4; }
  else if (idx4 < 98304)   { src = W_hh; dst = WhhB; off = idx4 - 49152; }
  else                     { src = Wk;   dst = WkB;  off = idx4 - 98304; }
  f32x4 v = *(const f32x4*)(src + 4*(size_t)off);
  s16x4 o; o[0]=f2bf(v[0]); o[1]=f2bf(v[1]); o[2]=f2bf(v[2]); o[3]=f2bf(v[3]);
  *(s16x4*)(dst + 4*(size_t)off) = o;
}

__global__ __launch_bounds__(256) void w_trans(
    const float* __restrict__ Wv, const float* __restrict__ W1,
    const float* __restrict__ W2, const float* __restrict__ Wq,
    short* __restrict__ WvT, short* __restrict__ W1T,
    short* __restrict__ W2T, short* __restrict__ WqT)
{
  __shared__ float tile[64][65];
  int bid = blockIdx.x, t = threadIdx.x;
  const float* src; short* dst; int R, C, tr, tc;
  if (bid < 16)      { src = Wv; dst = WvT; R = 256; C = 256; int q = bid;      tr = q >> 2; tc = q & 3; }
  else if (bid < 48) { src = W1; dst = W1T; R = 256; C = 512; int q = bid - 16; tr = q >> 3; tc = q & 7; }
  else if (bid < 80) { src = W2; dst = W2T; R = 512; C = 256; int q = bid - 48; tr = q >> 2; tc = q & 3; }
  else               { src = Wq; dst = WqT; R = 256; C = 256; int q = bid - 80; tr = q >> 2; tc = q & 3; }
  int r0 = tr*64, c0 = tc*64;
  for (int p = t; p < 4096; p += 256) {
    int rr = p >> 6, cc = p & 63;
    tile[rr][cc] = src[(size_t)(r0 + rr)*C + c0 + cc];
  }
  __syncthreads();
  for (int p = t; p < 4096; p += 256) {
    int cc = p >> 6, rr = p & 63;
    dst[(size_t)(c0 + cc)*R + r0 + rr] = f2bf(tile[rr][cc]);
  }
}

// ---------------------------------------------------------------------------
__global__ __launch_bounds__(256) void s0_prep(
    const float* __restrict__ slots_init,
    const float* __restrict__ ln_s_g, const float* __restrict__ ln_s_b,
    const float* __restrict__ Wq, const float* __restrict__ bq,
    const float* __restrict__ Wk, const float* __restrict__ bk,
    float* __restrict__ slots_cur, short* __restrict__ qk, float* __restrict__ qb)
{
  __shared__ float red[8];
  __shared__ float sln[256], qv[256];
  int b = blockIdx.x >> 3, i = blockIdx.x & 7;
  int t = threadIdx.x;
  int row_base = (b*NSLOT + i)*256;
  float si = slots_init[row_base + t];
  slots_cur[row_base + t] = si;
  float s = si, s2 = si*si;
  #pragma unroll
  for (int m = 1; m < 64; m <<= 1) { s += __shfl_xor(s, m); s2 += __shfl_xor(s2, m); }
  if ((t & 63) == 0) { red[t >> 6] = s; red[4 + (t >> 6)] = s2; }
  __syncthreads();
  s  = red[0] + red[1] + red[2] + red[3];
  s2 = red[4] + red[5] + red[6] + red[7];
  float mu = s*(1.f/256.f), var = s2*(1.f/256.f) - mu*mu;
  float rs = 1.f/sqrtf(var + LNEPS);
  sln[t] = (si - mu)*rs*ln_s_g[t] + ln_s_b[t];
  __syncthreads();
  float acc = bq[t];
  for (int c = 0; c < 256; ++c) acc += sln[c]*Wq[(c << 8) + t];
  qv[t] = acc;
  __syncthreads();
  float a0 = 0.f, a1 = 0.f, a2 = 0.f, a3 = 0.f;
  const float* wr = Wk + ((size_t)t << 8);
  for (int d = 0; d < 64; ++d) {
    a0 += qv[d]*wr[d];         a1 += qv[64+d]*wr[64+d];
    a2 += qv[128+d]*wr[128+d]; a3 += qv[192+d]*wr[192+d];
  }
  short* qrow = qk + (size_t)(b*R32 + i*4)*256 + t;
  qrow[0]   = f2bf(SCALE_F*a0);
  qrow[256] = f2bf(SCALE_F*a1);
  qrow[512] = f2bf(SCALE_F*a2);
  qrow[768] = f2bf(SCALE_F*a3);
  int h = t >> 6, d2 = t & 63;
  float pv = qv[h*64 + d2]*bk[h*64 + d2];
  #pragma unroll
  for (int m = 1; m < 64; m <<= 1) pv += __shfl_xor(pv, m);
  if (d2 == 0) qb[b*R32 + i*4 + h] = SCALE_F*pv;
}

// ---------------------------------------------------------------------------
// xln_prep: LN(x) once -> bf16 xln [b][j][256], xlnT [b][256][4096], xsum64.
// grid 2048 = (b, 64-row tile), 256 thr. ldsT column index is XOR-swizzled by
// (c>>3)&7 so the per-row writes (uniform column, 8-way bank alias at stride
// 72 shorts) land on 8 distinct banks; the b128 reads apply the same XOR.
// ---------------------------------------------------------------------------
__global__ __launch_bounds__(256) void xln_prep(
    const float* __restrict__ inp,
    const float* __restrict__ ln_f_g, const float* __restrict__ ln_f_b,
    short* __restrict__ xln, short* __restrict__ xlnT, float* __restrict__ xsum64)
{
  __shared__ short ldsT[256*72];      // [c][jlocal] stride 72, col ^ ((c>>3&7)<<3)
  __shared__ float xsred[4][256];
  int b = blockIdx.x >> 6, jt = blockIdx.x & 63;
  int t = threadIdx.x, w = t >> 6, lane = t & 63;
  float gc[4], bc[4];
  #pragma unroll
  for (int q = 0; q < 4; ++q) { gc[q] = ln_f_g[lane + 64*q]; bc[q] = ln_f_b[lane + 64*q]; }
  float xsum_acc[4] = {0.f,0.f,0.f,0.f};
  #pragma unroll 4
  for (int rr = 0; rr < 16; ++rr) {
    int jl = w*16 + rr;
    size_t row = ((size_t)b*SEQN + jt*64 + jl) << 8;
    const float* rp = inp + row;
    float v0 = rp[lane], v1 = rp[lane+64], v2 = rp[lane+128], v3 = rp[lane+192];
    float s  = v0 + v1 + v2 + v3;
    float s2 = v0*v0 + v1*v1 + v2*v2 + v3*v3;
    #pragma unroll
    for (int m = 1; m < 64; m <<= 1) { s += __shfl_xor(s, m); s2 += __shfl_xor(s2, m); }
    float mu = s*(1.f/256.f), var = s2*(1.f/256.f) - mu*mu;
    float rs = 1.f/sqrtf(var + LNEPS);
    float vv[4] = {v0, v1, v2, v3};
    #pragma unroll
    for (int q = 0; q < 4; ++q) {
      float xl = (vv[q] - mu)*rs*gc[q] + bc[q];
      xsum_acc[q] += xl;
      short hv = f2bf(xl);
      xln[row + lane + 64*q] = hv;
      int c = lane + 64*q;
      ldsT[c*72 + (jl ^ (((c >> 3) & 7) << 3))] = hv;
    }
  }
  #pragma unroll
  for (int q = 0; q < 4; ++q) xsred[w][lane + 64*q] = xsum_acc[q];
  __syncthreads();
  xsum64[(((size_t)b*64 + jt) << 8) + t] =
      xsred[0][t] + xsred[1][t] + xsred[2][t] + xsred[3][t];
  // write transposed tile: [256 c][64 j], 8 c-rows x 128B per instr
  #pragma unroll
  for (int it = 0; it < 8; ++it) {
    int cr = it*32 + (t >> 3);
    int j0 = (t & 7)*8;
    s16x8 v = *(const s16x8*)(ldsT + cr*72 + (j0 ^ (((cr >> 3) & 7) << 3)));
    *(s16x8*)(xlnT + (((size_t)b*256 + cr) << 12) + jt*64 + j0) = v;
  }
}

// ---------------------------------------------------------------------------
// attn2: grid 512 = (b, chunk of 256 j), 256 thr, 4 steps of 64 j.
// Reads xln/xlnT bf16; XOR-swizzled xs/xt/ps (bits 3..4 of k-index by row&3).
// ---------------------------------------------------------------------------
#define A2_XS   0
#define A2_XT   (64*264*2)                  // 33792
#define A2_PS   (A2_XT + 256*72*2)          // 70656
#define A2_PSUM (A2_PS + 32*72*2)           // 75264
#define A2_QB   (A2_PSUM + 128*4)           // 75776
#define A2_BYTES (A2_QB + 32*4)             // 75904

__global__ __launch_bounds__(256, 2) void attn2_kernel(
    const short* __restrict__ xln, const short* __restrict__ xlnT,
    const short* __restrict__ qk, const float* __restrict__ qb,
    float* __restrict__ A_part, float* __restrict__ psum_part)
{
  extern __shared__ char smem[];
  short* xs       = (short*)(smem + A2_XS);
  short* xt       = (short*)(smem + A2_XT);
  short* ps       = (short*)(smem + A2_PS);
  float* psum_lds = (float*)(smem + A2_PSUM);
  float* qb_lds   = (float*)(smem + A2_QB);

  int tid = threadIdx.x;
  int w = tid >> 6, lane = tid & 63;
  int g = lane >> 4, lj = lane & 15;
  int b = blockIdx.x >> 4, chunk = blockIdx.x & 15;
  int xr3 = (lj & 3) << 3;   // read-side XOR for all frag reads

  if (tid < 32) qb_lds[tid] = qb[b*R32 + tid];

  s16x8 qkf[2][8];
  #pragma unroll
  for (int mt = 0; mt < 2; ++mt)
    #pragma unroll
    for (int ks = 0; ks < 8; ++ks)
      qkf[mt][ks] = *(const s16x8*)(qk + ((size_t)(b*R32 + mt*16 + lj) << 8) + ks*32 + g*8);
  __syncthreads();

  float qb0[4], qb1[4];
  #pragma unroll
  for (int r = 0; r < 4; ++r) { qb0[r] = qb_lds[4*g + r]; qb1[r] = qb_lds[16 + 4*g + r]; }

  f32x4 zero4 = {0.f, 0.f, 0.f, 0.f};
  f32x4 accD[2][4];
  #pragma unroll
  for (int mt = 0; mt < 2; ++mt)
    #pragma unroll
    for (int nt = 0; nt < 4; ++nt) accD[mt][nt] = zero4;
  float psum_acc[8] = {0.f,0.f,0.f,0.f,0.f,0.f,0.f,0.f};

  for (int step = 0; step < 4; ++step) {
    int jbase = chunk*256 + step*64;
    // ---- stage xs (row-major) ----
    const short* xrow = xln + (((size_t)b*SEQN + jbase) << 8);
    #pragma unroll
    for (int grp = 0; grp < 2; ++grp) {
      int tr = w*16 + (grp*2 + (lane >> 5))*4;     // 4-aligned
      int c0 = (lane & 31)*8;
      s16x8 rv[4];
      #pragma unroll
      for (int k = 0; k < 4; ++k) rv[k] = *(const s16x8*)(xrow + ((size_t)(tr + k) << 8) + c0);
      #pragma unroll
      for (int k = 0; k < 4; ++k)
        *(s16x8*)(xs + (tr + k)*264 + (c0 ^ (k << 3))) = rv[k];
    }
    // ---- stage xt (col-major) ----
    const short* xtr = xlnT + (((size_t)b*256) << 12) + jbase;
    #pragma unroll
    for (int it = 0; it < 8; ++it) {
      int cr = w*64 + it*8 + (lane >> 3);
      int j0 = (lane & 7)*8;
      s16x8 v = *(const s16x8*)(xtr + ((size_t)cr << 12) + j0);
      *(s16x8*)(xt + cr*72 + (j0 ^ ((cr & 3) << 3))) = v;
    }
    // ---- GEMM1 on this wave's own 16 j (same-wave LDS, no barrier) ----
    f32x4 d0 = zero4, d1 = zero4;
    #pragma unroll
    for (int ks = 0; ks < 8; ++ks) {
      s16x8 bx = *(const s16x8*)(xs + (w*16 + lj)*264 + ((ks*32 + g*8) ^ xr3));
      d0 = __builtin_amdgcn_mfma_f32_16x16x32_bf16(qkf[0][ks], bx, d0, 0, 0, 0);
      d1 = __builtin_amdgcn_mfma_f32_16x16x32_bf16(qkf[1][ks], bx, d1, 0, 0, 0);
    }
    // ---- softmax over 32 rows per column ----
    {
      float m0 = -1e30f;
      #pragma unroll
      for (int r = 0; r < 4; ++r) {
        m0 = fmaxf(m0, d0[r] + qb0[r]);
        m0 = fmaxf(m0, d1[r] + qb1[r]);
      }
      m0 = fmaxf(m0, __shfl_xor(m0, 16));
      m0 = fmaxf(m0, __shfl_xor(m0, 32));
      float e0[4], e1[4], ssum = 0.f;
      #pragma unroll
      for (int r = 0; r < 4; ++r) {
        e0[r] = __expf(d0[r] + qb0[r] - m0);
        e1[r] = __expf(d1[r] + qb1[r] - m0);
        ssum += e0[r] + e1[r];
      }
      ssum += __shfl_xor(ssum, 16);
      ssum += __shfl_xor(ssum, 32);
      float inv = 1.f/ssum;
      int jl = w*16 + lj;
      #pragma unroll
      for (int r = 0; r < 4; ++r) {
        float sm0 = e0[r]*inv, sm1 = e1[r]*inv;
        psum_acc[r]     += sm0;
        psum_acc[4 + r] += sm1;
        int jx = jl ^ (r << 3);
        ps[(4*g + r)*72 + jx]      = f2bf(sm0);
        ps[(16 + 4*g + r)*72 + jx] = f2bf(sm1);
      }
    }
    __syncthreads();
    // ---- GEMM2 ----
    #pragma unroll
    for (int ks = 0; ks < 2; ++ks) {
      int kx = (ks*32 + g*8) ^ xr3;
      s16x8 pa0 = *(const s16x8*)(ps + lj*72 + kx);
      s16x8 pa1 = *(const s16x8*)(ps + (16 + lj)*72 + kx);
      #pragma unroll
      for (int nt = 0; nt < 4; ++nt) {
        s16x8 bxt = *(const s16x8*)(xt + (w*64 + nt*16 + lj)*72 + kx);
        accD[0][nt] = __builtin_amdgcn_mfma_f32_16x16x32_bf16(pa0, bxt, accD[0][nt], 0, 0, 0);
        accD[1][nt] = __builtin_amdgcn_mfma_f32_16x16x32_bf16(pa1, bxt, accD[1][nt], 0, 0, 0);
      }
    }
    __syncthreads();
  }

  {
    float* ap = A_part + ((size_t)(b*16 + chunk) << 13);
    #pragma unroll
    for (int mt = 0; mt < 2; ++mt)
      #pragma unroll
      for (int nt = 0; nt < 4; ++nt)
        #pragma unroll
        for (int r = 0; r < 4; ++r)
          ap[(mt*16 + 4*g + r)*256 + w*64 + nt*16 + lj] = accD[mt][nt][r];
  }
  #pragma unroll
  for (int r = 0; r < 8; ++r)
    #pragma unroll
    for (int m = 1; m < 16; m <<= 1) psum_acc[r] += __shfl_xor(psum_acc[r], m);
  if (lj == 0) {
    #pragma unroll
    for (int r = 0; r < 4; ++r) {
      psum_lds[w*32 + 4*g + r]      = psum_acc[r];
      psum_lds[w*32 + 16 + 4*g + r] = psum_acc[4 + r];
    }
  }
  __syncthreads();
  if (tid < 32) {
    float sv = psum_lds[tid] + psum_lds[32+tid] + psum_lds[64+tid] + psum_lds[96+tid];
    psum_part[(b*16 + chunk)*32 + tid] = sv;
  }
}

// ---------------------------------------------------------------------------
// attn (fallback, LN inline) — proven round-1 kernel, unchanged.
// ---------------------------------------------------------------------------
#define XSTR 264
#define TSTR 72
#define PSTR 72
#define OFF_XT   (64*XSTR*2)
#define OFF_PS   (OFF_XT + 256*TSTR*2)
#define OFF_PSUM (OFF_PS + 32*PSTR*2)
#define OFF_XSUM (OFF_PSUM + 4*32*4)
#define OFF_QB   (OFF_XSUM + 4*256*4)
#define SMEM_BYTES (OFF_QB + 32*4)   // 80000

__global__ __launch_bounds__(256, 2) void attn_kernel(
    const float* __restrict__ inp,
    const float* __restrict__ ln_f_g, const float* __restrict__ ln_f_b,
    const short* __restrict__ qk, const float* __restrict__ qb,
    float* __restrict__ A_part, float* __restrict__ psum_part,
    float* __restrict__ xsum_part, int write_xsum)
{
  extern __shared__ char smem[];
  short* xs       = (short*)smem;
  short* xt       = (short*)(smem + OFF_XT);
  short* ps       = (short*)(smem + OFF_PS);
  float* psum_lds = (float*)(smem + OFF_PSUM);
  float* xsum_lds = (float*)(smem + OFF_XSUM);
  float* qb_lds   = (float*)(smem + OFF_QB);

  int tid = threadIdx.x;
  int w = tid >> 6, lane = tid & 63;
  int g = lane >> 4, lj = lane & 15;
  int b = blockIdx.x >> 4, chunk = blockIdx.x & 15;

  float gc[4], bc[4];
  #pragma unroll
  for (int q = 0; q < 4; ++q) { gc[q] = ln_f_g[lane + 64*q]; bc[q] = ln_f_b[lane + 64*q]; }

  if (tid < 32) qb_lds[tid] = qb[b*R32 + tid];

  s16x8 qkf[2][8];
  #pragma unroll
  for (int mt = 0; mt < 2; ++mt)
    #pragma unroll
    for (int ks = 0; ks < 8; ++ks)
      qkf[mt][ks] = *(const s16x8*)(qk + ((size_t)(b*R32 + mt*16 + lj) << 8) + ks*32 + g*8);
  __syncthreads();

  float qb0[4], qb1[4];
  #pragma unroll
  for (int r = 0; r < 4; ++r) { qb0[r] = qb_lds[4*g + r]; qb1[r] = qb_lds[16 + 4*g + r]; }

  f32x4 zero4 = {0.f, 0.f, 0.f, 0.f};
  f32x4 accD[2][4];
  #pragma unroll
  for (int mt = 0; mt < 2; ++mt)
    #pragma unroll
    for (int nt = 0; nt < 4; ++nt) accD[mt][nt] = zero4;
  float psum_acc[8] = {0.f,0.f,0.f,0.f,0.f,0.f,0.f,0.f};
  float xsum_acc[4] = {0.f,0.f,0.f,0.f};

  for (int step = 0; step < 4; ++step) {
    int jbase = chunk*256 + step*64;
    const float* rowp = inp + (((size_t)b*SEQN + jbase + w*16) << 8);
    short tq[4][4];
    #pragma unroll
    for (int rr = 0; rr < 16; ++rr) {
      const float* rp = rowp + ((size_t)rr << 8);
      float v0 = rp[lane], v1 = rp[lane+64], v2 = rp[lane+128], v3 = rp[lane+192];
      float s  = v0 + v1 + v2 + v3;
      float s2 = v0*v0 + v1*v1 + v2*v2 + v3*v3;
      #pragma unroll
      for (int m = 1; m < 64; m <<= 1) { s += __shfl_xor(s, m); s2 += __shfl_xor(s2, m); }
      float mu = s*(1.f/256.f);
      float var = s2*(1.f/256.f) - mu*mu;
      float rs = 1.f/sqrtf(var + LNEPS);
      int jrow = w*16 + rr;
      float vv[4] = {v0, v1, v2, v3};
      #pragma unroll
      for (int q = 0; q < 4; ++q) {
        float xl = (vv[q] - mu)*rs*gc[q] + bc[q];
        xsum_acc[q] += xl;
        short hv = f2bf(xl);
        xs[jrow*XSTR + lane + 64*q] = hv;
        tq[q][rr & 3] = hv;
      }
      if ((rr & 3) == 3) {
        #pragma unroll
        for (int q = 0; q < 4; ++q) {
          s16x4 pk = { tq[q][0], tq[q][1], tq[q][2], tq[q][3] };
          *(s16x4*)(xt + (lane + 64*q)*TSTR + w*16 + (rr - 3)) = pk;
        }
      }
    }
    f32x4 d0 = zero4, d1 = zero4;
    #pragma unroll
    for (int ks = 0; ks < 8; ++ks) {
      s16x8 bx = *(const s16x8*)(xs + (w*16 + lj)*XSTR + ks*32 + g*8);
      d0 = __builtin_amdgcn_mfma_f32_16x16x32_bf16(qkf[0][ks], bx, d0, 0, 0, 0);
      d1 = __builtin_amdgcn_mfma_f32_16x16x32_bf16(qkf[1][ks], bx, d1, 0, 0, 0);
    }
    {
      float m0 = -1e30f;
      #pragma unroll
      for (int r = 0; r < 4; ++r) {
        m0 = fmaxf(m0, d0[r] + qb0[r]);
        m0 = fmaxf(m0, d1[r] + qb1[r]);
      }
      m0 = fmaxf(m0, __shfl_xor(m0, 16));
      m0 = fmaxf(m0, __shfl_xor(m0, 32));
      float e0[4], e1[4], ssum = 0.f;
      #pragma unroll
      for (int r = 0; r < 4; ++r) {
        e0[r] = __expf(d0[r] + qb0[r] - m0);
        e1[r] = __expf(d1[r] + qb1[r] - m0);
        ssum += e0[r] + e1[r];
      }
      ssum += __shfl_xor(ssum, 16);
      ssum += __shfl_xor(ssum, 32);
      float inv = 1.f/ssum;
      int jl = w*16 + lj;
      #pragma unroll
      for (int r = 0; r < 4; ++r) {
        float sm0 = e0[r]*inv, sm1 = e1[r]*inv;
        psum_acc[r]     += sm0;
        psum_acc[4 + r] += sm1;
        ps[(4*g + r)*PSTR + jl]      = f2bf(sm0);
        ps[(16 + 4*g + r)*PSTR + jl] = f2bf(sm1);
      }
    }
    __syncthreads();
    #pragma unroll
    for (int ks = 0; ks < 2; ++ks) {
      s16x8 pa0 = *(const s16x8*)(ps + lj*PSTR + ks*32 + g*8);
      s16x8 pa1 = *(const s16x8*)(ps + (16 + lj)*PSTR + ks*32 + g*8);
      #pragma unroll
      for (int nt = 0; nt < 4; ++nt) {
        s16x8 bxt = *(const s16x8*)(xt + (w*64 + nt*16 + lj)*TSTR + ks*32 + g*8);
        accD[0][nt] = __builtin_amdgcn_mfma_f32_16x16x32_bf16(pa0, bxt, accD[0][nt], 0, 0, 0);
        accD[1][nt] = __builtin_amdgcn_mfma_f32_16x16x32_bf16(pa1, bxt, accD[1][nt], 0, 0, 0);
      }
    }
    __syncthreads();
  }

  {
    float* ap = A_part + ((size_t)(b*16 + chunk) << 13);
    #pragma unroll
    for (int mt = 0; mt < 2; ++mt)
      #pragma unroll
      for (int nt = 0; nt < 4; ++nt)
        #pragma unroll
        for (int r = 0; r < 4; ++r)
          ap[(mt*16 + 4*g + r)*256 + w*64 + nt*16 + lj] = accD[mt][nt][r];
  }
  #pragma unroll
  for (int r = 0; r < 8; ++r)
    #pragma unroll
    for (int m = 1; m < 16; m <<= 1) psum_acc[r] += __shfl_xor(psum_acc[r], m);
  if (lj == 0) {
    #pragma unroll
    for (int r = 0; r < 4; ++r) {
      psum_lds[w*32 + 4*g + r]      = psum_acc[r];
      psum_lds[w*32 + 16 + 4*g + r] = psum_acc[4 + r];
    }
  }
  #pragma unroll
  for (int q = 0; q < 4; ++q) xsum_lds[w*256 + lane + 64*q] = xsum_acc[q];
  __syncthreads();
  if (tid < 32) {
    float sv = psum_lds[tid] + psum_lds[32+tid] + psum_lds[64+tid] + psum_lds[96+tid];
    psum_part[(b*16 + chunk)*32 + tid] = sv;
  }
  if (write_xsum) {
    float sv = xsum_lds[tid] + xsum_lds[256+tid] + xsum_lds[512+tid] + xsum_lds[768+tid];
    xsum_part[((b*16 + chunk) << 8) + tid] = sv;
  }
}

// ---------------------------------------------------------------------------
// s3a: wide reduce A_part(+eps*xsum)/Sr -> bf16 AfB. grid 128 = (b, r-octet).
// ---------------------------------------------------------------------------
__global__ __launch_bounds__(256) void s3a_reduce(
    const float* __restrict__ A_part, const float* __restrict__ psum_part,
    const float* __restrict__ xsum_part, int nchx, short* __restrict__ AfB)
{
  __shared__ float SrL[8];
  int b = blockIdx.x >> 2, rg = blockIdx.x & 3;
  int t = threadIdx.x;
  if (t < 8) {
    float p = 0.f;
    for (int ch = 0; ch < 16; ++ch) p += psum_part[(b*16 + ch)*32 + rg*8 + t];
    SrL[t] = p + 4096.f*EPSA;
  }
  float xsv = 0.f;
  for (int ch = 0; ch < nchx; ++ch) xsv += xsum_part[(((size_t)b*nchx + ch) << 8) + t];
  __syncthreads();
  #pragma unroll 1
  for (int k = 0; k < 8; ++k) {
    int r = rg*8 + k;
    float a = 0.f;
    #pragma unroll
    for (int ch = 0; ch < 16; ++ch)
      a += A_part[((size_t)((b*16 + ch)*32 + r) << 8) + t];
    AfB[((size_t)(b*32 + r) << 8) + t] = f2bf((a + EPSA*xsv) / SrL[k]);
  }
}

// ---------------------------------------------------------------------------
// s3b: grid 128 = (b, slot-pair), 512 thr. Per-thread bf16-weight dots with
// wave-uniform LDS broadcast of activations. Full GRU+MLP+next-q chain.
// ---------------------------------------------------------------------------
__global__ __launch_bounds__(512) void s3b_update(
    const short* __restrict__ AfB,
    const short* __restrict__ WihB, const short* __restrict__ WhhB,
    const short* __restrict__ WkB,  const short* __restrict__ WvT,
    const short* __restrict__ W1T,  const short* __restrict__ W2T,
    const short* __restrict__ WqT,
    const float* __restrict__ bv,   const float* __restrict__ b_ih,
    const float* __restrict__ b_hh,
    const float* __restrict__ ln_ff_g, const float* __restrict__ ln_ff_b,
    const float* __restrict__ b1,   const float* __restrict__ b2,
    const float* __restrict__ ln_s_g, const float* __restrict__ ln_s_b,
    const float* __restrict__ bq,   const float* __restrict__ bk,
    float* __restrict__ slots_cur, short* __restrict__ qk,
    float* __restrict__ qb, float* __restrict__ out)
{
  __shared__ float Af[2][4][256];
  __shared__ float hp[2][256], uu[2][256], rz[2][512];
  __shared__ float inn[2][256], hnn[2][256], snl[2][256], lns[2][256];
  __shared__ float hhh[2][512], qv[2][256];
  __shared__ float red[2][4][2];

  int b = blockIdx.x >> 2, p = blockIdx.x & 3;
  int t = threadIdx.x;
  int sl = t >> 8, u = t & 255;
  int si = p*2 + sl;
  int row_base = (b*8 + si)*256;

  // stage 0
  #pragma unroll
  for (int k = 0; k < 4; ++k)
    Af[sl][k][u] = bf2f(AfB[((size_t)(b*32 + si*4 + k) << 8) + u]);
  hp[sl][u] = slots_cur[row_base + u];
  __syncthreads();

  // stage 1: uu = Af_head @ WvT + bv
  uu[sl][u] = bv[u] + dotw(WvT + ((size_t)u << 8), Af[sl][u >> 6], 256);
  __syncthreads();

  // stage 2: GRU gate matvecs
  #pragma unroll
  for (int rep = 0; rep < 2; ++rep) {
    int n = rep*256 + u;
    rz[sl][n] = b_ih[n] + b_hh[n]
              + dotw(WihB + ((size_t)n << 8), uu[sl], 256)
              + dotw(WhhB + ((size_t)n << 8), hp[sl], 256);
  }
  inn[sl][u] = b_ih[512 + u] + dotw(WihB + ((size_t)(512 + u) << 8), uu[sl], 256);
  hnn[sl][u] = b_hh[512 + u] + dotw(WhhB + ((size_t)(512 + u) << 8), hp[sl], 256);
  __syncthreads();

  // stage 3: gates
  {
    float rg = 1.f/(1.f + __expf(-rz[sl][u]));
    float zg = 1.f/(1.f + __expf(-rz[sl][256 + u]));
    float ng = tanhf(inn[sl][u] + rg*hnn[sl][u]);
    snl[sl][u] = (1.f - zg)*ng + zg*hp[sl][u];
  }
  __syncthreads();

  // stage 4: LN_ff
  {
    float v = snl[sl][u];
    float s = v, s2 = v*v;
    #pragma unroll
    for (int m = 1; m < 64; m <<= 1) { s += __shfl_xor(s, m); s2 += __shfl_xor(s2, m); }
    int ww = (t >> 6) & 3;
    if ((t & 63) == 0) { red[sl][ww][0] = s; red[sl][ww][1] = s2; }
    __syncthreads();
    s  = red[sl][0][0] + red[sl][1][0] + red[sl][2][0] + red[sl][3][0];
    s2 = red[sl][0][1] + red[sl][1][1] + red[sl][2][1] + red[sl][3][1];
    float mu = s*(1.f/256.f), var = s2*(1.f/256.f) - mu*mu;
    float rs = 1.f/sqrtf(var + LNEPS);
    lns[sl][u] = (snl[sl][u] - mu)*rs*ln_ff_g[u] + ln_ff_b[u];
  }
  __syncthreads();

  // stage 5: MLP1
  #pragma unroll
  for (int rep = 0; rep < 2; ++rep) {
    int n = rep*256 + u;
    hhh[sl][n] = fmaxf(b1[n] + dotw(W1T + ((size_t)n << 8), lns[sl], 256), 0.f);
  }
  __syncthreads();

  // stage 6: MLP2 + residual
  {
    float o = b2[u] + dotw(W2T + ((size_t)u << 9), hhh[sl], 512);
    float sfin = snl[sl][u] + o;
    snl[sl][u] = sfin;
    out[row_base + u] = sfin;
    slots_cur[row_base + u] = sfin;
  }
  __syncthreads();

  // stage 7: LN_s + qv
  {
    float v = snl[sl][u];
    float s = v, s2 = v*v;
    #pragma unroll
    for (int m = 1; m < 64; m <<= 1) { s += __shfl_xor(s, m); s2 += __shfl_xor(s2, m); }
    int ww = (t >> 6) & 3;
    if ((t & 63) == 0) { red[sl][ww][0] = s; red[sl][ww][1] = s2; }
    __syncthreads();
    s  = red[sl][0][0] + red[sl][1][0] + red[sl][2][0] + red[sl][3][0];
    s2 = red[sl][0][1] + red[sl][1][1] + red[sl][2][1] + red[sl][3][1];
    float mu = s*(1.f/256.f), var = s2*(1.f/256.f) - mu*mu;
    float rs = 1.f/sqrtf(var + LNEPS);
    lns[sl][u] = (snl[sl][u] - mu)*rs*ln_s_g[u] + ln_s_b[u];
  }
  __syncthreads();
  qv[sl][u] = bq[u] + dotw(WqT + ((size_t)u << 8), lns[sl], 256);
  __syncthreads();

  // stage 8: qk~ + qb
  #pragma unroll
  for (int h = 0; h < 4; ++h) {
    float acc = dotw(WkB + ((size_t)u << 8) + h*64, &qv[sl][h*64], 64);
    qk[((size_t)(b*R32 + si*4 + h) << 8) + u] = f2bf(SCALE_F*acc);
  }
  if (u < 32) {
    int h = u >> 3, dg = u & 7;
    float pv = 0.f;
    #pragma unroll
    for (int d = 0; d < 8; ++d) pv += qv[sl][h*64 + dg*8 + d]*bk[h*64 + dg*8 + d];
    pv += __shfl_xor(pv, 1); pv += __shfl_xor(pv, 2); pv += __shfl_xor(pv, 4);
    if (dg == 0) qb[b*R32 + si*4 + h] = SCALE_F*pv;
  }
}

// ---------------------------------------------------------------------------
extern "C" void kernel_launch(void* const* d_in, const int* in_sizes, int n_in,
                              void* d_out, int out_size, void* d_ws, size_t ws_size,
                              hipStream_t stream) {
  (void)in_sizes; (void)n_in; (void)out_size;
  const float* inp        = (const float*)d_in[0];
  const float* slots_init = (const float*)d_in[1];
  const float* ln_f_g = (const float*)d_in[2];
  const float* ln_f_b = (const float*)d_in[3];
  const float* ln_s_g = (const float*)d_in[4];
  const float* ln_s_b = (const float*)d_in[5];
  const float* ln_ff_g = (const float*)d_in[6];
  const float* ln_ff_b = (const float*)d_in[7];
  const float* Wq = (const float*)d_in[8];
  const float* bq = (const float*)d_in[9];
  const float* Wk = (const float*)d_in[10];
  const float* bk = (const float*)d_in[11];
  const float* Wv = (const float*)d_in[12];
  const float* bv = (const float*)d_in[13];
  const float* W_ih = (const float*)d_in[14];
  const float* b_ih = (const float*)d_in[15];
  const float* W_hh = (const float*)d_in[16];
  const float* b_hh = (const float*)d_in[17];
  const float* W1 = (const float*)d_in[18];
  const float* b1 = (const float*)d_in[19];
  const float* W2 = (const float*)d_in[20];
  const float* b2 = (const float*)d_in[21];
  float* out = (float*)d_out;

  const size_t NEED_BIG = 156176384ULL;
  bool big = ws_size >= NEED_BIG;
  int nchx = big ? 64 : 16;

  char* ws = (char*)d_ws;
  size_t o = 0;
  auto alloc = [&](size_t bytes) { size_t r = o; o += (bytes + 255) & ~(size_t)255; return r; };
  float* A_part    = (float*)(ws + alloc(16777216));
  float* psum_part = (float*)(ws + alloc(65536));
  float* xsum_part = (float*)(ws + alloc(big ? 2097152 : 524288));
  short* qk        = (short*)(ws + alloc(524288));
  float* qbuf      = (float*)(ws + alloc(4096));
  float* slots_cur = (float*)(ws + alloc(262144));
  short* AfB       = (short*)(ws + alloc(524288));
  short* WihB      = (short*)(ws + alloc(393216));
  short* WhhB      = (short*)(ws + alloc(393216));
  short* WkB       = (short*)(ws + alloc(131072));
  short* WvT       = (short*)(ws + alloc(131072));
  short* W1T       = (short*)(ws + alloc(262144));
  short* W2T       = (short*)(ws + alloc(262144));
  short* WqT       = (short*)(ws + alloc(131072));
  short* xln  = nullptr;
  short* xlnT = nullptr;
  if (big) {
    xln  = (short*)(ws + alloc(67108864));
    xlnT = (short*)(ws + alloc(67108864));
  }

  hipFuncSetAttribute((const void*)attn_kernel,
                      hipFuncAttributeMaxDynamicSharedMemorySize, SMEM_BYTES);
  hipFuncSetAttribute((const void*)attn2_kernel,
                      hipFuncAttributeMaxDynamicSharedMemorySize, A2_BYTES);

  w_cast<<<448, 256, 0, stream>>>(W_ih, W_hh, Wk, WihB, WhhB, WkB);
  w_trans<<<96, 256, 0, stream>>>(Wv, W1, W2, Wq, WvT, W1T, W2T, WqT);
  s0_prep<<<256, 256, 0, stream>>>(slots_init, ln_s_g, ln_s_b, Wq, bq, Wk, bk,
                                   slots_cur, qk, qbuf);
  if (big) {
    xln_prep<<<2048, 256, 0, stream>>>(inp, ln_f_g, ln_f_b, xln, xlnT, xsum_part);
  }
  for (int it = 0; it < 5; ++it) {
    if (big) {
      attn2_kernel<<<512, 256, A2_BYTES, stream>>>(xln, xlnT, qk, qbuf,
                                                   A_part, psum_part);
    } else {
      attn_kernel<<<512, 256, SMEM_BYTES, stream>>>(inp, ln_f_g, ln_f_b, qk, qbuf,
                                                    A_part, psum_part, xsum_part,
                                                    it == 0 ? 1 : 0);
    }
    s3a_reduce<<<128, 256, 0, stream>>>(A_part, psum_part, xsum_part, nchx, AfB);
    s3b_update<<<128, 512, 0, stream>>>(AfB, WihB, WhhB, WkB, WvT, W1T, W2T, WqT,
                                        bv, b_ih, b_hh, ln_ff_g, ln_ff_b,
                                        b1, b2, ln_s_g, ln_s_b, bq, bk,
                                        slots_cur, qk, qbuf, out);
  }
}

// Round 5
// 848.981 us; speedup vs baseline: 1.2704x; 1.2704x over previous
//
#include <hip/hip_runtime.h>
#include <stdint.h>

// MultiHeadSlotAttention on MI355X (gfx950).
// dots = (SCALE*q@Wk_h^T).x_ln + SCALE*q.bk ; updates = ((sum_j p*x_ln + EPS*xsum)/S)@Wv + bv
// K/V never materialized. LN(x) precomputed ONCE to bf16 (row-major + transposed).
// Per iteration: MFMA attention pass (attn2) + fused update kernel (s3u, grid 256,
// column-major bf16 weights -> coalesced loads + LDS-broadcast activations).

#define NSLOT 8
#define R32   32
#define SEQN  4096

constexpr float EPSA    = 1e-8f;
constexpr float LNEPS   = 1e-5f;
constexpr float SCALE_F = 0.125f;

typedef short s16x8 __attribute__((ext_vector_type(8)));
typedef short s16x4 __attribute__((ext_vector_type(4)));
typedef float f32x4 __attribute__((ext_vector_type(4)));

__device__ __forceinline__ short f2bf(float f) {
  uint32_t u = __float_as_uint(f);
  uint32_t r = (u + 0x7FFFu + ((u >> 16) & 1u)) >> 16;
  return (short)r;
}
__device__ __forceinline__ float bf2f(short s) {
  return __uint_as_float(((uint32_t)(uint16_t)s) << 16);
}
// column-dot: out[n] accumulation over c of x[c] (LDS, wave-uniform broadcast)
// times W[c][n] (global bf16, coalesced across lanes). ldn = row length of W.
__device__ __forceinline__ float coldot(const short* __restrict__ W, int ldn, int n,
                                        const float* __restrict__ x, int c0, int cnt) {
  const short* wp = W + (size_t)c0*ldn + n;
  float acc = 0.f;
  #pragma unroll 8
  for (int i = 0; i < cnt; ++i) { acc += bf2f(*wp) * x[c0 + i]; wp += ldn; }
  return acc;
}

// ---------------------------------------------------------------------------
// w_castB: direct bf16 casts of Wv, W1, W2, Wq (already [in][out]). 384 blocks.
// ---------------------------------------------------------------------------
__global__ __launch_bounds__(256) void w_castB(
    const float* __restrict__ Wv, const float* __restrict__ W1,
    const float* __restrict__ W2, const float* __restrict__ Wq,
    short* __restrict__ WvB, short* __restrict__ W1B,
    short* __restrict__ W2B, short* __restrict__ WqB)
{
  int idx4 = blockIdx.x*256 + threadIdx.x;
  const float* src; short* dst; int off;
  if (idx4 < 16384)        { src = Wv; dst = WvB; off = idx4; }
  else if (idx4 < 49152)   { src = W1; dst = W1B; off = idx4 - 16384; }
  else if (idx4 < 81920)   { src = W2; dst = W2B; off = idx4 - 49152; }
  else                     { src = Wq; dst = WqB; off = idx4 - 81920; }
  f32x4 v = *(const f32x4*)(src + 4*(size_t)off);
  s16x4 o; o[0]=f2bf(v[0]); o[1]=f2bf(v[1]); o[2]=f2bf(v[2]); o[3]=f2bf(v[3]);
  *(s16x4*)(dst + 4*(size_t)off) = o;
}

// ---------------------------------------------------------------------------
// w_transB: W_ih[768][256] -> WihT[256][768]; W_hh likewise; Wk[256][256] -> WkT.
// 112 blocks of 64x64 tiles.
// ---------------------------------------------------------------------------
__global__ __launch_bounds__(256) void w_transB(
    const float* __restrict__ W_ih, const float* __restrict__ W_hh,
    const float* __restrict__ Wk,
    short* __restrict__ WihT, short* __restrict__ WhhT, short* __restrict__ WkT)
{
  __shared__ float tile[64][65];
  int bid = blockIdx.x, t = threadIdx.x;
  const float* src; short* dst; int R, C, tr, tc;
  if (bid < 48)      { src = W_ih; dst = WihT; R = 768; C = 256; int q = bid;      tr = q >> 2; tc = q & 3; }
  else if (bid < 96) { src = W_hh; dst = WhhT; R = 768; C = 256; int q = bid - 48; tr = q >> 2; tc = q & 3; }
  else               { src = Wk;   dst = WkT;  R = 256; C = 256; int q = bid - 96; tr = q >> 2; tc = q & 3; }
  int r0 = tr*64, c0 = tc*64;
  for (int p = t; p < 4096; p += 256) {
    int rr = p >> 6, cc = p & 63;
    tile[rr][cc] = src[(size_t)(r0 + rr)*C + c0 + cc];
  }
  __syncthreads();
  for (int p = t; p < 4096; p += 256) {
    int cc = p >> 6, rr = p & 63;
    dst[(size_t)(c0 + cc)*R + r0 + rr] = f2bf(tile[rr][cc]);
  }
}

// ---------------------------------------------------------------------------
__global__ __launch_bounds__(256) void s0_prep(
    const float* __restrict__ slots_init,
    const float* __restrict__ ln_s_g, const float* __restrict__ ln_s_b,
    const float* __restrict__ Wq, const float* __restrict__ bq,
    const float* __restrict__ Wk, const float* __restrict__ bk,
    float* __restrict__ slots_cur, short* __restrict__ qk, float* __restrict__ qb)
{
  __shared__ float red[8];
  __shared__ float sln[256], qv[256];
  int b = blockIdx.x >> 3, i = blockIdx.x & 7;
  int t = threadIdx.x;
  int row_base = (b*NSLOT + i)*256;
  float si = slots_init[row_base + t];
  slots_cur[row_base + t] = si;
  float s = si, s2 = si*si;
  #pragma unroll
  for (int m = 1; m < 64; m <<= 1) { s += __shfl_xor(s, m); s2 += __shfl_xor(s2, m); }
  if ((t & 63) == 0) { red[t >> 6] = s; red[4 + (t >> 6)] = s2; }
  __syncthreads();
  s  = red[0] + red[1] + red[2] + red[3];
  s2 = red[4] + red[5] + red[6] + red[7];
  float mu = s*(1.f/256.f), var = s2*(1.f/256.f) - mu*mu;
  float rs = 1.f/sqrtf(var + LNEPS);
  sln[t] = (si - mu)*rs*ln_s_g[t] + ln_s_b[t];
  __syncthreads();
  float acc = bq[t];
  for (int c = 0; c < 256; ++c) acc += sln[c]*Wq[(c << 8) + t];
  qv[t] = acc;
  __syncthreads();
  float a0 = 0.f, a1 = 0.f, a2 = 0.f, a3 = 0.f;
  const float* wr = Wk + ((size_t)t << 8);
  for (int d = 0; d < 64; ++d) {
    a0 += qv[d]*wr[d];         a1 += qv[64+d]*wr[64+d];
    a2 += qv[128+d]*wr[128+d]; a3 += qv[192+d]*wr[192+d];
  }
  short* qrow = qk + (size_t)(b*R32 + i*4)*256 + t;
  qrow[0]   = f2bf(SCALE_F*a0);
  qrow[256] = f2bf(SCALE_F*a1);
  qrow[512] = f2bf(SCALE_F*a2);
  qrow[768] = f2bf(SCALE_F*a3);
  int h = t >> 6, d2 = t & 63;
  float pv = qv[h*64 + d2]*bk[h*64 + d2];
  #pragma unroll
  for (int m = 1; m < 64; m <<= 1) pv += __shfl_xor(pv, m);
  if (d2 == 0) qb[b*R32 + i*4 + h] = SCALE_F*pv;
}

// ---------------------------------------------------------------------------
// xln_prep: LN(x) once -> bf16 xln [b][j][256], xlnT [b][256][4096], xsum64.
// ---------------------------------------------------------------------------
__global__ __launch_bounds__(256) void xln_prep(
    const float* __restrict__ inp,
    const float* __restrict__ ln_f_g, const float* __restrict__ ln_f_b,
    short* __restrict__ xln, short* __restrict__ xlnT, float* __restrict__ xsum64)
{
  __shared__ short ldsT[256*72];      // [c][jlocal] stride 72, col ^ ((c>>3&7)<<3)
  __shared__ float xsred[4][256];
  int b = blockIdx.x >> 6, jt = blockIdx.x & 63;
  int t = threadIdx.x, w = t >> 6, lane = t & 63;
  float gc[4], bc[4];
  #pragma unroll
  for (int q = 0; q < 4; ++q) { gc[q] = ln_f_g[lane + 64*q]; bc[q] = ln_f_b[lane + 64*q]; }
  float xsum_acc[4] = {0.f,0.f,0.f,0.f};
  #pragma unroll 4
  for (int rr = 0; rr < 16; ++rr) {
    int jl = w*16 + rr;
    size_t row = ((size_t)b*SEQN + jt*64 + jl) << 8;
    const float* rp = inp + row;
    float v0 = rp[lane], v1 = rp[lane+64], v2 = rp[lane+128], v3 = rp[lane+192];
    float s  = v0 + v1 + v2 + v3;
    float s2 = v0*v0 + v1*v1 + v2*v2 + v3*v3;
    #pragma unroll
    for (int m = 1; m < 64; m <<= 1) { s += __shfl_xor(s, m); s2 += __shfl_xor(s2, m); }
    float mu = s*(1.f/256.f), var = s2*(1.f/256.f) - mu*mu;
    float rs = 1.f/sqrtf(var + LNEPS);
    float vv[4] = {v0, v1, v2, v3};
    #pragma unroll
    for (int q = 0; q < 4; ++q) {
      float xl = (vv[q] - mu)*rs*gc[q] + bc[q];
      xsum_acc[q] += xl;
      short hv = f2bf(xl);
      xln[row + lane + 64*q] = hv;
      int c = lane + 64*q;
      ldsT[c*72 + (jl ^ (((c >> 3) & 7) << 3))] = hv;
    }
  }
  #pragma unroll
  for (int q = 0; q < 4; ++q) xsred[w][lane + 64*q] = xsum_acc[q];
  __syncthreads();
  xsum64[(((size_t)b*64 + jt) << 8) + t] =
      xsred[0][t] + xsred[1][t] + xsred[2][t] + xsred[3][t];
  #pragma unroll
  for (int it = 0; it < 8; ++it) {
    int cr = it*32 + (t >> 3);
    int j0 = (t & 7)*8;
    s16x8 v = *(const s16x8*)(ldsT + cr*72 + (j0 ^ (((cr >> 3) & 7) << 3)));
    *(s16x8*)(xlnT + (((size_t)b*256 + cr) << 12) + jt*64 + j0) = v;
  }
}

// ---------------------------------------------------------------------------
// xsum_final: reduce per-chunk xsum -> xsumF[b][256]. grid 32.
// ---------------------------------------------------------------------------
__global__ __launch_bounds__(256) void xsum_final(
    const float* __restrict__ xsum_part, int nch, float* __restrict__ xsumF)
{
  int b = blockIdx.x, t = threadIdx.x;
  float s = 0.f;
  for (int ch = 0; ch < nch; ++ch) s += xsum_part[(((size_t)b*nch + ch) << 8) + t];
  xsumF[b*256 + t] = s;
}

// ---------------------------------------------------------------------------
// attn2: grid 512 = (b, chunk of 256 j), 256 thr, 4 steps of 64 j.
// ---------------------------------------------------------------------------
#define A2_XS   0
#define A2_XT   (64*264*2)                  // 33792
#define A2_PS   (A2_XT + 256*72*2)          // 70656
#define A2_PSUM (A2_PS + 32*72*2)           // 75264
#define A2_QB   (A2_PSUM + 128*4)           // 75776
#define A2_BYTES (A2_QB + 32*4)             // 75904

__global__ __launch_bounds__(256, 2) void attn2_kernel(
    const short* __restrict__ xln, const short* __restrict__ xlnT,
    const short* __restrict__ qk, const float* __restrict__ qb,
    float* __restrict__ A_part, float* __restrict__ psum_part)
{
  extern __shared__ char smem[];
  short* xs       = (short*)(smem + A2_XS);
  short* xt       = (short*)(smem + A2_XT);
  short* ps       = (short*)(smem + A2_PS);
  float* psum_lds = (float*)(smem + A2_PSUM);
  float* qb_lds   = (float*)(smem + A2_QB);

  int tid = threadIdx.x;
  int w = tid >> 6, lane = tid & 63;
  int g = lane >> 4, lj = lane & 15;
  int b = blockIdx.x >> 4, chunk = blockIdx.x & 15;
  int xr3 = (lj & 3) << 3;

  if (tid < 32) qb_lds[tid] = qb[b*R32 + tid];

  s16x8 qkf[2][8];
  #pragma unroll
  for (int mt = 0; mt < 2; ++mt)
    #pragma unroll
    for (int ks = 0; ks < 8; ++ks)
      qkf[mt][ks] = *(const s16x8*)(qk + ((size_t)(b*R32 + mt*16 + lj) << 8) + ks*32 + g*8);
  __syncthreads();

  float qb0[4], qb1[4];
  #pragma unroll
  for (int r = 0; r < 4; ++r) { qb0[r] = qb_lds[4*g + r]; qb1[r] = qb_lds[16 + 4*g + r]; }

  f32x4 zero4 = {0.f, 0.f, 0.f, 0.f};
  f32x4 accD[2][4];
  #pragma unroll
  for (int mt = 0; mt < 2; ++mt)
    #pragma unroll
    for (int nt = 0; nt < 4; ++nt) accD[mt][nt] = zero4;
  float psum_acc[8] = {0.f,0.f,0.f,0.f,0.f,0.f,0.f,0.f};

  for (int step = 0; step < 4; ++step) {
    int jbase = chunk*256 + step*64;
    const short* xrow = xln + (((size_t)b*SEQN + jbase) << 8);
    #pragma unroll
    for (int grp = 0; grp < 2; ++grp) {
      int tr = w*16 + (grp*2 + (lane >> 5))*4;
      int c0 = (lane & 31)*8;
      s16x8 rv[4];
      #pragma unroll
      for (int k = 0; k < 4; ++k) rv[k] = *(const s16x8*)(xrow + ((size_t)(tr + k) << 8) + c0);
      #pragma unroll
      for (int k = 0; k < 4; ++k)
        *(s16x8*)(xs + (tr + k)*264 + (c0 ^ (k << 3))) = rv[k];
    }
    const short* xtr = xlnT + (((size_t)b*256) << 12) + jbase;
    #pragma unroll
    for (int it = 0; it < 8; ++it) {
      int cr = w*64 + it*8 + (lane >> 3);
      int j0 = (lane & 7)*8;
      s16x8 v = *(const s16x8*)(xtr + ((size_t)cr << 12) + j0);
      *(s16x8*)(xt + cr*72 + (j0 ^ ((cr & 3) << 3))) = v;
    }
    f32x4 d0 = zero4, d1 = zero4;
    #pragma unroll
    for (int ks = 0; ks < 8; ++ks) {
      s16x8 bx = *(const s16x8*)(xs + (w*16 + lj)*264 + ((ks*32 + g*8) ^ xr3));
      d0 = __builtin_amdgcn_mfma_f32_16x16x32_bf16(qkf[0][ks], bx, d0, 0, 0, 0);
      d1 = __builtin_amdgcn_mfma_f32_16x16x32_bf16(qkf[1][ks], bx, d1, 0, 0, 0);
    }
    {
      float m0 = -1e30f;
      #pragma unroll
      for (int r = 0; r < 4; ++r) {
        m0 = fmaxf(m0, d0[r] + qb0[r]);
        m0 = fmaxf(m0, d1[r] + qb1[r]);
      }
      m0 = fmaxf(m0, __shfl_xor(m0, 16));
      m0 = fmaxf(m0, __shfl_xor(m0, 32));
      float e0[4], e1[4], ssum = 0.f;
      #pragma unroll
      for (int r = 0; r < 4; ++r) {
        e0[r] = __expf(d0[r] + qb0[r] - m0);
        e1[r] = __expf(d1[r] + qb1[r] - m0);
        ssum += e0[r] + e1[r];
      }
      ssum += __shfl_xor(ssum, 16);
      ssum += __shfl_xor(ssum, 32);
      float inv = 1.f/ssum;
      int jl = w*16 + lj;
      #pragma unroll
      for (int r = 0; r < 4; ++r) {
        float sm0 = e0[r]*inv, sm1 = e1[r]*inv;
        psum_acc[r]     += sm0;
        psum_acc[4 + r] += sm1;
        int jx = jl ^ (r << 3);
        ps[(4*g + r)*72 + jx]      = f2bf(sm0);
        ps[(16 + 4*g + r)*72 + jx] = f2bf(sm1);
      }
    }
    __syncthreads();
    #pragma unroll
    for (int ks = 0; ks < 2; ++ks) {
      int kx = (ks*32 + g*8) ^ xr3;
      s16x8 pa0 = *(const s16x8*)(ps + lj*72 + kx);
      s16x8 pa1 = *(const s16x8*)(ps + (16 + lj)*72 + kx);
      #pragma unroll
      for (int nt = 0; nt < 4; ++nt) {
        s16x8 bxt = *(const s16x8*)(xt + (w*64 + nt*16 + lj)*72 + kx);
        accD[0][nt] = __builtin_amdgcn_mfma_f32_16x16x32_bf16(pa0, bxt, accD[0][nt], 0, 0, 0);
        accD[1][nt] = __builtin_amdgcn_mfma_f32_16x16x32_bf16(pa1, bxt, accD[1][nt], 0, 0, 0);
      }
    }
    __syncthreads();
  }

  {
    float* ap = A_part + ((size_t)(b*16 + chunk) << 13);
    #pragma unroll
    for (int mt = 0; mt < 2; ++mt)
      #pragma unroll
      for (int nt = 0; nt < 4; ++nt)
        #pragma unroll
        for (int r = 0; r < 4; ++r)
          ap[(mt*16 + 4*g + r)*256 + w*64 + nt*16 + lj] = accD[mt][nt][r];
  }
  #pragma unroll
  for (int r = 0; r < 8; ++r)
    #pragma unroll
    for (int m = 1; m < 16; m <<= 1) psum_acc[r] += __shfl_xor(psum_acc[r], m);
  if (lj == 0) {
    #pragma unroll
    for (int r = 0; r < 4; ++r) {
      psum_lds[w*32 + 4*g + r]      = psum_acc[r];
      psum_lds[w*32 + 16 + 4*g + r] = psum_acc[4 + r];
    }
  }
  __syncthreads();
  if (tid < 32) {
    float sv = psum_lds[tid] + psum_lds[32+tid] + psum_lds[64+tid] + psum_lds[96+tid];
    psum_part[(b*16 + chunk)*32 + tid] = sv;
  }
}

// ---------------------------------------------------------------------------
// attn (fallback, LN inline) — proven round-1 kernel, unchanged.
// ---------------------------------------------------------------------------
#define XSTR 264
#define TSTR 72
#define PSTR 72
#define OFF_XT   (64*XSTR*2)
#define OFF_PS   (OFF_XT + 256*TSTR*2)
#define OFF_PSUM (OFF_PS + 32*PSTR*2)
#define OFF_XSUM (OFF_PSUM + 4*32*4)
#define OFF_QB   (OFF_XSUM + 4*256*4)
#define SMEM_BYTES (OFF_QB + 32*4)   // 80000

__global__ __launch_bounds__(256, 2) void attn_kernel(
    const float* __restrict__ inp,
    const float* __restrict__ ln_f_g, const float* __restrict__ ln_f_b,
    const short* __restrict__ qk, const float* __restrict__ qb,
    float* __restrict__ A_part, float* __restrict__ psum_part,
    float* __restrict__ xsum_part, int write_xsum)
{
  extern __shared__ char smem[];
  short* xs       = (short*)smem;
  short* xt       = (short*)(smem + OFF_XT);
  short* ps       = (short*)(smem + OFF_PS);
  float* psum_lds = (float*)(smem + OFF_PSUM);
  float* xsum_lds = (float*)(smem + OFF_XSUM);
  float* qb_lds   = (float*)(smem + OFF_QB);

  int tid = threadIdx.x;
  int w = tid >> 6, lane = tid & 63;
  int g = lane >> 4, lj = lane & 15;
  int b = blockIdx.x >> 4, chunk = blockIdx.x & 15;

  float gc[4], bc[4];
  #pragma unroll
  for (int q = 0; q < 4; ++q) { gc[q] = ln_f_g[lane + 64*q]; bc[q] = ln_f_b[lane + 64*q]; }

  if (tid < 32) qb_lds[tid] = qb[b*R32 + tid];

  s16x8 qkf[2][8];
  #pragma unroll
  for (int mt = 0; mt < 2; ++mt)
    #pragma unroll
    for (int ks = 0; ks < 8; ++ks)
      qkf[mt][ks] = *(const s16x8*)(qk + ((size_t)(b*R32 + mt*16 + lj) << 8) + ks*32 + g*8);
  __syncthreads();

  float qb0[4], qb1[4];
  #pragma unroll
  for (int r = 0; r < 4; ++r) { qb0[r] = qb_lds[4*g + r]; qb1[r] = qb_lds[16 + 4*g + r]; }

  f32x4 zero4 = {0.f, 0.f, 0.f, 0.f};
  f32x4 accD[2][4];
  #pragma unroll
  for (int mt = 0; mt < 2; ++mt)
    #pragma unroll
    for (int nt = 0; nt < 4; ++nt) accD[mt][nt] = zero4;
  float psum_acc[8] = {0.f,0.f,0.f,0.f,0.f,0.f,0.f,0.f};
  float xsum_acc[4] = {0.f,0.f,0.f,0.f};

  for (int step = 0; step < 4; ++step) {
    int jbase = chunk*256 + step*64;
    const float* rowp = inp + (((size_t)b*SEQN + jbase + w*16) << 8);
    short tq[4][4];
    #pragma unroll
    for (int rr = 0; rr < 16; ++rr) {
      const float* rp = rowp + ((size_t)rr << 8);
      float v0 = rp[lane], v1 = rp[lane+64], v2 = rp[lane+128], v3 = rp[lane+192];
      float s  = v0 + v1 + v2 + v3;
      float s2 = v0*v0 + v1*v1 + v2*v2 + v3*v3;
      #pragma unroll
      for (int m = 1; m < 64; m <<= 1) { s += __shfl_xor(s, m); s2 += __shfl_xor(s2, m); }
      float mu = s*(1.f/256.f);
      float var = s2*(1.f/256.f) - mu*mu;
      float rs = 1.f/sqrtf(var + LNEPS);
      int jrow = w*16 + rr;
      float vv[4] = {v0, v1, v2, v3};
      #pragma unroll
      for (int q = 0; q < 4; ++q) {
        float xl = (vv[q] - mu)*rs*gc[q] + bc[q];
        xsum_acc[q] += xl;
        short hv = f2bf(xl);
        xs[jrow*XSTR + lane + 64*q] = hv;
        tq[q][rr & 3] = hv;
      }
      if ((rr & 3) == 3) {
        #pragma unroll
        for (int q = 0; q < 4; ++q) {
          s16x4 pk = { tq[q][0], tq[q][1], tq[q][2], tq[q][3] };
          *(s16x4*)(xt + (lane + 64*q)*TSTR + w*16 + (rr - 3)) = pk;
        }
      }
    }
    f32x4 d0 = zero4, d1 = zero4;
    #pragma unroll
    for (int ks = 0; ks < 8; ++ks) {
      s16x8 bx = *(const s16x8*)(xs + (w*16 + lj)*XSTR + ks*32 + g*8);
      d0 = __builtin_amdgcn_mfma_f32_16x16x32_bf16(qkf[0][ks], bx, d0, 0, 0, 0);
      d1 = __builtin_amdgcn_mfma_f32_16x16x32_bf16(qkf[1][ks], bx, d1, 0, 0, 0);
    }
    {
      float m0 = -1e30f;
      #pragma unroll
      for (int r = 0; r < 4; ++r) {
        m0 = fmaxf(m0, d0[r] + qb0[r]);
        m0 = fmaxf(m0, d1[r] + qb1[r]);
      }
      m0 = fmaxf(m0, __shfl_xor(m0, 16));
      m0 = fmaxf(m0, __shfl_xor(m0, 32));
      float e0[4], e1[4], ssum = 0.f;
      #pragma unroll
      for (int r = 0; r < 4; ++r) {
        e0[r] = __expf(d0[r] + qb0[r] - m0);
        e1[r] = __expf(d1[r] + qb1[r] - m0);
        ssum += e0[r] + e1[r];
      }
      ssum += __shfl_xor(ssum, 16);
      ssum += __shfl_xor(ssum, 32);
      float inv = 1.f/ssum;
      int jl = w*16 + lj;
      #pragma unroll
      for (int r = 0; r < 4; ++r) {
        float sm0 = e0[r]*inv, sm1 = e1[r]*inv;
        psum_acc[r]     += sm0;
        psum_acc[4 + r] += sm1;
        ps[(4*g + r)*PSTR + jl]      = f2bf(sm0);
        ps[(16 + 4*g + r)*PSTR + jl] = f2bf(sm1);
      }
    }
    __syncthreads();
    #pragma unroll
    for (int ks = 0; ks < 2; ++ks) {
      s16x8 pa0 = *(const s16x8*)(ps + lj*PSTR + ks*32 + g*8);
      s16x8 pa1 = *(const s16x8*)(ps + (16 + lj)*PSTR + ks*32 + g*8);
      #pragma unroll
      for (int nt = 0; nt < 4; ++nt) {
        s16x8 bxt = *(const s16x8*)(xt + (w*64 + nt*16 + lj)*TSTR + ks*32 + g*8);
        accD[0][nt] = __builtin_amdgcn_mfma_f32_16x16x32_bf16(pa0, bxt, accD[0][nt], 0, 0, 0);
        accD[1][nt] = __builtin_amdgcn_mfma_f32_16x16x32_bf16(pa1, bxt, accD[1][nt], 0, 0, 0);
      }
    }
    __syncthreads();
  }

  {
    float* ap = A_part + ((size_t)(b*16 + chunk) << 13);
    #pragma unroll
    for (int mt = 0; mt < 2; ++mt)
      #pragma unroll
      for (int nt = 0; nt < 4; ++nt)
        #pragma unroll
        for (int r = 0; r < 4; ++r)
          ap[(mt*16 + 4*g + r)*256 + w*64 + nt*16 + lj] = accD[mt][nt][r];
  }
  #pragma unroll
  for (int r = 0; r < 8; ++r)
    #pragma unroll
    for (int m = 1; m < 16; m <<= 1) psum_acc[r] += __shfl_xor(psum_acc[r], m);
  if (lj == 0) {
    #pragma unroll
    for (int r = 0; r < 4; ++r) {
      psum_lds[w*32 + 4*g + r]      = psum_acc[r];
      psum_lds[w*32 + 16 + 4*g + r] = psum_acc[4 + r];
    }
  }
  #pragma unroll
  for (int q = 0; q < 4; ++q) xsum_lds[w*256 + lane + 64*q] = xsum_acc[q];
  __syncthreads();
  if (tid < 32) {
    float sv = psum_lds[tid] + psum_lds[32+tid] + psum_lds[64+tid] + psum_lds[96+tid];
    psum_part[(b*16 + chunk)*32 + tid] = sv;
  }
  if (write_xsum) {
    float sv = xsum_lds[tid] + xsum_lds[256+tid] + xsum_lds[512+tid] + xsum_lds[768+tid];
    xsum_part[((b*16 + chunk) << 8) + tid] = sv;
  }
}

// ---------------------------------------------------------------------------
// s3u: grid 256 = (b,slot), 512 thr. Fused A-reduce + GRU + MLP + next-q.
// Column-major bf16 weights: out[n]+=x[c]*W[c][n], n=thread -> coalesced.
// Activations broadcast from LDS (wave-uniform addresses).
// ---------------------------------------------------------------------------
__global__ __launch_bounds__(512) void s3u_update(
    const float* __restrict__ A_part, const float* __restrict__ psum_part,
    const float* __restrict__ xsumF,
    const short* __restrict__ WvB,  const short* __restrict__ WihT,
    const short* __restrict__ WhhT, const short* __restrict__ W1B,
    const short* __restrict__ W2B,  const short* __restrict__ WqB,
    const short* __restrict__ WkT,
    const float* __restrict__ bv,   const float* __restrict__ b_ih,
    const float* __restrict__ b_hh,
    const float* __restrict__ ln_ff_g, const float* __restrict__ ln_ff_b,
    const float* __restrict__ b1,   const float* __restrict__ b2,
    const float* __restrict__ ln_s_g, const float* __restrict__ ln_s_b,
    const float* __restrict__ bq,   const float* __restrict__ bk,
    float* __restrict__ slots_cur, short* __restrict__ qk,
    float* __restrict__ qb, float* __restrict__ out)
{
  __shared__ float af[4][256];
  __shared__ float hp[256], uu[256], rz[512], inn[256], hnn[256];
  __shared__ float snl[256], lns[256], hh[512], qv[256];
  __shared__ float part[2][256];
  __shared__ float SrL[4];
  __shared__ float red[8][2];

  int b = blockIdx.x >> 3, si = blockIdx.x & 7;
  int t = threadIdx.x;
  int u = t & 255, half = t >> 8;
  int row_base = (b*8 + si)*256;

  // ---- stage 0: Sr, hp, Af (coalesced A_part reduce) ----
  if (t < 4) {
    float p = 0.f;
    for (int ch = 0; ch < 16; ++ch) p += psum_part[(b*16 + ch)*32 + si*4 + t];
    SrL[t] = p + 4096.f*EPSA;
  }
  if (t < 256) hp[t] = slots_cur[row_base + t];
  #pragma unroll
  for (int rep = 0; rep < 2; ++rep) {
    int k = half*2 + rep;
    float a = 0.f;
    #pragma unroll
    for (int ch = 0; ch < 16; ++ch)
      a += A_part[((size_t)((b*16 + ch)*32 + si*4 + k) << 8) + u];
    af[k][u] = a;
  }
  __syncthreads();
  {
    float xs = xsumF[b*256 + u];
    #pragma unroll
    for (int rep = 0; rep < 2; ++rep) {
      int k = half*2 + rep;
      af[k][u] = (af[k][u] + EPSA*xs) / SrL[k];
    }
  }
  __syncthreads();

  // ---- stage 1: uu = Af_head @ Wv + bv  (K-split across halves) ----
  {
    int hd = u >> 6;                   // wave-uniform
    part[half][u] = coldot(WvB, 256, u, af[hd], half*128, 128);
  }
  __syncthreads();
  if (t < 256) uu[u] = part[0][u] + part[1][u] + bv[u];
  __syncthreads();

  // ---- stage 2: GRU gate matvecs ----
  rz[t] = b_ih[t] + b_hh[t]
        + coldot(WihT, 768, t, uu, 0, 256)
        + coldot(WhhT, 768, t, hp, 0, 256);
  if (half == 0) inn[u] = b_ih[512 + u] + coldot(WihT, 768, 512 + u, uu, 0, 256);
  else           hnn[u] = b_hh[512 + u] + coldot(WhhT, 768, 512 + u, hp, 0, 256);
  __syncthreads();

  // ---- stage 3: gates ----
  if (t < 256) {
    float rg = 1.f/(1.f + __expf(-rz[u]));
    float zg = 1.f/(1.f + __expf(-rz[256 + u]));
    float ng = tanhf(inn[u] + rg*hnn[u]);
    snl[u] = (1.f - zg)*ng + zg*hp[u];
  }
  __syncthreads();

  // ---- stage 4: LN_ff ----
  {
    float v = (t < 256) ? snl[t] : 0.f;
    float s = v, s2 = v*v;
    #pragma unroll
    for (int m = 1; m < 64; m <<= 1) { s += __shfl_xor(s, m); s2 += __shfl_xor(s2, m); }
    int wv = t >> 6;
    if ((t & 63) == 0) { red[wv][0] = s; red[wv][1] = s2; }
    __syncthreads();
    s = 0.f; s2 = 0.f;
    #pragma unroll
    for (int k = 0; k < 8; ++k) { s += red[k][0]; s2 += red[k][1]; }
    float mu = s*(1.f/256.f), var = s2*(1.f/256.f) - mu*mu;
    float rs = 1.f/sqrtf(var + LNEPS);
    if (t < 256) lns[u] = (snl[u] - mu)*rs*ln_ff_g[u] + ln_ff_b[u];
  }
  __syncthreads();

  // ---- stage 5: MLP1 ----
  hh[t] = fmaxf(b1[t] + coldot(W1B, 512, t, lns, 0, 256), 0.f);
  __syncthreads();

  // ---- stage 6: MLP2 + residual (K-split) ----
  part[half][u] = coldot(W2B, 256, u, hh, half*256, 256);
  __syncthreads();
  if (t < 256) {
    float sfin = snl[u] + part[0][u] + part[1][u] + b2[u];
    snl[u] = sfin;
    out[row_base + u] = sfin;
    slots_cur[row_base + u] = sfin;
  }
  __syncthreads();

  // ---- stage 7: LN_s -> lns ; qv (K-split) ----
  {
    float v = (t < 256) ? snl[t] : 0.f;
    float s = v, s2 = v*v;
    #pragma unroll
    for (int m = 1; m < 64; m <<= 1) { s += __shfl_xor(s, m); s2 += __shfl_xor(s2, m); }
    int wv = t >> 6;
    if ((t & 63) == 0) { red[wv][0] = s; red[wv][1] = s2; }
    __syncthreads();
    s = 0.f; s2 = 0.f;
    #pragma unroll
    for (int k = 0; k < 8; ++k) { s += red[k][0]; s2 += red[k][1]; }
    float mu = s*(1.f/256.f), var = s2*(1.f/256.f) - mu*mu;
    float rs = 1.f/sqrtf(var + LNEPS);
    if (t < 256) lns[u] = (snl[u] - mu)*rs*ln_s_g[u] + ln_s_b[u];
  }
  __syncthreads();
  part[half][u] = coldot(WqB, 256, u, lns, half*128, 128);
  __syncthreads();
  if (t < 256) qv[u] = part[0][u] + part[1][u] + bq[u];
  __syncthreads();

  // ---- stage 8: qk~ rows (si*4 + h), h split across halves; qb ----
  #pragma unroll
  for (int rep = 0; rep < 2; ++rep) {
    int h = half*2 + rep;
    float acc = coldot(WkT, 256, u, qv, h*64, 64);
    qk[((size_t)(b*R32 + si*4 + h) << 8) + u] = f2bf(SCALE_F*acc);
  }
  if (t < 32) {
    int h = t >> 3, dg = t & 7;
    float pv = 0.f;
    #pragma unroll
    for (int d = 0; d < 8; ++d) pv += qv[h*64 + dg*8 + d]*bk[h*64 + dg*8 + d];
    pv += __shfl_xor(pv, 1); pv += __shfl_xor(pv, 2); pv += __shfl_xor(pv, 4);
    if (dg == 0) qb[b*R32 + si*4 + h] = SCALE_F*pv;
  }
}

// ---------------------------------------------------------------------------
extern "C" void kernel_launch(void* const* d_in, const int* in_sizes, int n_in,
                              void* d_out, int out_size, void* d_ws, size_t ws_size,
                              hipStream_t stream) {
  (void)in_sizes; (void)n_in; (void)out_size;
  const float* inp        = (const float*)d_in[0];
  const float* slots_init = (const float*)d_in[1];
  const float* ln_f_g = (const float*)d_in[2];
  const float* ln_f_b = (const float*)d_in[3];
  const float* ln_s_g = (const float*)d_in[4];
  const float* ln_s_b = (const float*)d_in[5];
  const float* ln_ff_g = (const float*)d_in[6];
  const float* ln_ff_b = (const float*)d_in[7];
  const float* Wq = (const float*)d_in[8];
  const float* bq = (const float*)d_in[9];
  const float* Wk = (const float*)d_in[10];
  const float* bk = (const float*)d_in[11];
  const float* Wv = (const float*)d_in[12];
  const float* bv = (const float*)d_in[13];
  const float* W_ih = (const float*)d_in[14];
  const float* b_ih = (const float*)d_in[15];
  const float* W_hh = (const float*)d_in[16];
  const float* b_hh = (const float*)d_in[17];
  const float* W1 = (const float*)d_in[18];
  const float* b1 = (const float*)d_in[19];
  const float* W2 = (const float*)d_in[20];
  const float* b2 = (const float*)d_in[21];
  float* out = (float*)d_out;

  const size_t NEED_BIG = 155684864ULL;
  bool big = ws_size >= NEED_BIG;
  int nchx = big ? 64 : 16;

  char* ws = (char*)d_ws;
  size_t o = 0;
  auto alloc = [&](size_t bytes) { size_t r = o; o += (bytes + 255) & ~(size_t)255; return r; };
  float* A_part    = (float*)(ws + alloc(16777216));
  float* psum_part = (float*)(ws + alloc(65536));
  float* xsum_part = (float*)(ws + alloc(big ? 2097152 : 524288));
  short* qk        = (short*)(ws + alloc(524288));
  float* qbuf      = (float*)(ws + alloc(4096));
  float* slots_cur = (float*)(ws + alloc(262144));
  float* xsumF     = (float*)(ws + alloc(32768));
  short* WvB       = (short*)(ws + alloc(131072));
  short* W1B       = (short*)(ws + alloc(262144));
  short* W2B       = (short*)(ws + alloc(262144));
  short* WqB       = (short*)(ws + alloc(131072));
  short* WihT      = (short*)(ws + alloc(393216));
  short* WhhT      = (short*)(ws + alloc(393216));
  short* WkT       = (short*)(ws + alloc(131072));
  short* xln  = nullptr;
  short* xlnT = nullptr;
  if (big) {
    xln  = (short*)(ws + alloc(67108864));
    xlnT = (short*)(ws + alloc(67108864));
  }

  hipFuncSetAttribute((const void*)attn_kernel,
                      hipFuncAttributeMaxDynamicSharedMemorySize, SMEM_BYTES);
  hipFuncSetAttribute((const void*)attn2_kernel,
                      hipFuncAttributeMaxDynamicSharedMemorySize, A2_BYTES);

  w_castB<<<384, 256, 0, stream>>>(Wv, W1, W2, Wq, WvB, W1B, W2B, WqB);
  w_transB<<<112, 256, 0, stream>>>(W_ih, W_hh, Wk, WihT, WhhT, WkT);
  s0_prep<<<256, 256, 0, stream>>>(slots_init, ln_s_g, ln_s_b, Wq, bq, Wk, bk,
                                   slots_cur, qk, qbuf);
  if (big) {
    xln_prep<<<2048, 256, 0, stream>>>(inp, ln_f_g, ln_f_b, xln, xlnT, xsum_part);
    xsum_final<<<32, 256, 0, stream>>>(xsum_part, nchx, xsumF);
  }
  for (int it = 0; it < 5; ++it) {
    if (big) {
      attn2_kernel<<<512, 256, A2_BYTES, stream>>>(xln, xlnT, qk, qbuf,
                                                   A_part, psum_part);
    } else {
      attn_kernel<<<512, 256, SMEM_BYTES, stream>>>(inp, ln_f_g, ln_f_b, qk, qbuf,
                                                    A_part, psum_part, xsum_part,
                                                    it == 0 ? 1 : 0);
      if (it == 0) xsum_final<<<32, 256, 0, stream>>>(xsum_part, nchx, xsumF);
    }
    s3u_update<<<256, 512, 0, stream>>>(A_part, psum_part, xsumF,
                                        WvB, WihT, WhhT, W1B, W2B, WqB, WkT,
                                        bv, b_ih, b_hh, ln_ff_g, ln_ff_b,
                                        b1, b2, ln_s_g, ln_s_b, bq, bk,
                                        slots_cur, qk, qbuf, out);
  }
}

// Round 7
// 781.627 us; speedup vs baseline: 1.3799x; 1.0862x over previous
//
#include <hip/hip_runtime.h>
#include <stdint.h>

// MultiHeadSlotAttention on MI355X (gfx950).
// dots = (SCALE*q@Wk_h^T).x_ln + SCALE*q.bk ; updates = ((sum_j p*x_ln + EPS*xsum)/S)@Wv + bv
// K/V never materialized. LN(x) precomputed once to bf16 (row-major + transposed).
// Per iteration: MFMA attention pass (attn2) + MFMA update kernel (s3m: grid 32,
// M=8 rows padded to 16, row-major bf16 weights streamed 16B/lane as MFMA B-operand).

#define NSLOT 8
#define R32   32
#define SEQN  4096

constexpr float EPSA    = 1e-8f;
constexpr float LNEPS   = 1e-5f;
constexpr float SCALE_F = 0.125f;

typedef short s16x8 __attribute__((ext_vector_type(8)));
typedef short s16x4 __attribute__((ext_vector_type(4)));
typedef float f32x4 __attribute__((ext_vector_type(4)));

__device__ __forceinline__ short f2bf(float f) {
  uint32_t u = __float_as_uint(f);
  uint32_t r = (u + 0x7FFFu + ((u >> 16) & 1u)) >> 16;
  return (short)r;
}
__device__ __forceinline__ float bf2f(short s) {
  return __uint_as_float(((uint32_t)(uint16_t)s) << 16);
}

// ---------------------------------------------------------------------------
// w_prep2: Wgru[512][512] = [W_ih rows 0..511 | W_hh rows 0..511] (cols 0..255 ih,
// 256..511 hh); WihNN/WhhNN = rows 512..767; WkB = cast Wk. 448 blocks x 256.
// ---------------------------------------------------------------------------
__global__ __launch_bounds__(256) void w_prep2(
    const float* __restrict__ W_ih, const float* __restrict__ W_hh,
    const float* __restrict__ Wk,
    short* __restrict__ Wgru, short* __restrict__ WihNN,
    short* __restrict__ WhhNN, short* __restrict__ WkB)
{
  int u = blockIdx.x*256 + threadIdx.x;   // 4-elem unit, total 114688
  const float* src; short* dst;
  if (u < 65536) {
    int flat = u*4, n = flat >> 9, c = flat & 511;
    src = (c < 256) ? (W_ih + (size_t)n*256 + c) : (W_hh + (size_t)n*256 + (c - 256));
    dst = Wgru + (size_t)n*512 + c;
  } else if (u < 81920) {
    int flat = (u - 65536)*4;
    src = W_ih + (size_t)(512 + (flat >> 8))*256 + (flat & 255);
    dst = WihNN + flat;
  } else if (u < 98304) {
    int flat = (u - 81920)*4;
    src = W_hh + (size_t)(512 + (flat >> 8))*256 + (flat & 255);
    dst = WhhNN + flat;
  } else {
    int flat = (u - 98304)*4;
    src = Wk + flat;
    dst = WkB + flat;
  }
  f32x4 v = *(const f32x4*)src;
  s16x4 o; o[0]=f2bf(v[0]); o[1]=f2bf(v[1]); o[2]=f2bf(v[2]); o[3]=f2bf(v[3]);
  *(s16x4*)dst = o;
}

// ---------------------------------------------------------------------------
// w_trans: fp32 [R][C] -> bf16 [C][R] (Wv, W1, W2, Wq). 96 blocks x 256.
// ---------------------------------------------------------------------------
__global__ __launch_bounds__(256) void w_trans(
    const float* __restrict__ Wv, const float* __restrict__ W1,
    const float* __restrict__ W2, const float* __restrict__ Wq,
    short* __restrict__ WvT, short* __restrict__ W1T,
    short* __restrict__ W2T, short* __restrict__ WqT)
{
  __shared__ float tile[64][65];
  int bid = blockIdx.x, t = threadIdx.x;
  const float* src; short* dst; int R, C, tr, tc;
  if (bid < 16)      { src = Wv; dst = WvT; R = 256; C = 256; int q = bid;      tr = q >> 2; tc = q & 3; }
  else if (bid < 48) { src = W1; dst = W1T; R = 256; C = 512; int q = bid - 16; tr = q >> 3; tc = q & 7; }
  else if (bid < 80) { src = W2; dst = W2T; R = 512; C = 256; int q = bid - 48; tr = q >> 2; tc = q & 3; }
  else               { src = Wq; dst = WqT; R = 256; C = 256; int q = bid - 80; tr = q >> 2; tc = q & 3; }
  int r0 = tr*64, c0 = tc*64;
  for (int p = t; p < 4096; p += 256) {
    int rr = p >> 6, cc = p & 63;
    tile[rr][cc] = src[(size_t)(r0 + rr)*C + c0 + cc];
  }
  __syncthreads();
  for (int p = t; p < 4096; p += 256) {
    int cc = p >> 6, rr = p & 63;
    dst[(size_t)(c0 + cc)*R + r0 + rr] = f2bf(tile[rr][cc]);
  }
}

// ---------------------------------------------------------------------------
__global__ __launch_bounds__(256) void s0_prep(
    const float* __restrict__ slots_init,
    const float* __restrict__ ln_s_g, const float* __restrict__ ln_s_b,
    const float* __restrict__ Wq, const float* __restrict__ bq,
    const float* __restrict__ Wk, const float* __restrict__ bk,
    float* __restrict__ slots_cur, short* __restrict__ qk, float* __restrict__ qb)
{
  __shared__ float red[8];
  __shared__ float sln[256], qv[256];
  int b = blockIdx.x >> 3, i = blockIdx.x & 7;
  int t = threadIdx.x;
  int row_base = (b*NSLOT + i)*256;
  float si = slots_init[row_base + t];
  slots_cur[row_base + t] = si;
  float s = si, s2 = si*si;
  #pragma unroll
  for (int m = 1; m < 64; m <<= 1) { s += __shfl_xor(s, m); s2 += __shfl_xor(s2, m); }
  if ((t & 63) == 0) { red[t >> 6] = s; red[4 + (t >> 6)] = s2; }
  __syncthreads();
  s  = red[0] + red[1] + red[2] + red[3];
  s2 = red[4] + red[5] + red[6] + red[7];
  float mu = s*(1.f/256.f), var = s2*(1.f/256.f) - mu*mu;
  float rs = 1.f/sqrtf(var + LNEPS);
  sln[t] = (si - mu)*rs*ln_s_g[t] + ln_s_b[t];
  __syncthreads();
  float acc = bq[t];
  for (int c = 0; c < 256; ++c) acc += sln[c]*Wq[(c << 8) + t];
  qv[t] = acc;
  __syncthreads();
  float a0 = 0.f, a1 = 0.f, a2 = 0.f, a3 = 0.f;
  const float* wr = Wk + ((size_t)t << 8);
  for (int d = 0; d < 64; ++d) {
    a0 += qv[d]*wr[d];         a1 += qv[64+d]*wr[64+d];
    a2 += qv[128+d]*wr[128+d]; a3 += qv[192+d]*wr[192+d];
  }
  short* qrow = qk + (size_t)(b*R32 + i*4)*256 + t;
  qrow[0]   = f2bf(SCALE_F*a0);
  qrow[256] = f2bf(SCALE_F*a1);
  qrow[512] = f2bf(SCALE_F*a2);
  qrow[768] = f2bf(SCALE_F*a3);
  int h = t >> 6, d2 = t & 63;
  float pv = qv[h*64 + d2]*bk[h*64 + d2];
  #pragma unroll
  for (int m = 1; m < 64; m <<= 1) pv += __shfl_xor(pv, m);
  if (d2 == 0) qb[b*R32 + i*4 + h] = SCALE_F*pv;
}

// ---------------------------------------------------------------------------
// xln_prep: LN(x) once -> bf16 xln [b][j][256], xlnT [b][256][4096], xsum64.
// ---------------------------------------------------------------------------
__global__ __launch_bounds__(256) void xln_prep(
    const float* __restrict__ inp,
    const float* __restrict__ ln_f_g, const float* __restrict__ ln_f_b,
    short* __restrict__ xln, short* __restrict__ xlnT, float* __restrict__ xsum64)
{
  __shared__ short ldsT[256*72];
  __shared__ float xsred[4][256];
  int b = blockIdx.x >> 6, jt = blockIdx.x & 63;
  int t = threadIdx.x, w = t >> 6, lane = t & 63;
  float gc[4], bc[4];
  #pragma unroll
  for (int q = 0; q < 4; ++q) { gc[q] = ln_f_g[lane + 64*q]; bc[q] = ln_f_b[lane + 64*q]; }
  float xsum_acc[4] = {0.f,0.f,0.f,0.f};
  #pragma unroll 4
  for (int rr = 0; rr < 16; ++rr) {
    int jl = w*16 + rr;
    size_t row = ((size_t)b*SEQN + jt*64 + jl) << 8;
    const float* rp = inp + row;
    float v0 = rp[lane], v1 = rp[lane+64], v2 = rp[lane+128], v3 = rp[lane+192];
    float s  = v0 + v1 + v2 + v3;
    float s2 = v0*v0 + v1*v1 + v2*v2 + v3*v3;
    #pragma unroll
    for (int m = 1; m < 64; m <<= 1) { s += __shfl_xor(s, m); s2 += __shfl_xor(s2, m); }
    float mu = s*(1.f/256.f), var = s2*(1.f/256.f) - mu*mu;
    float rs = 1.f/sqrtf(var + LNEPS);
    float vv[4] = {v0, v1, v2, v3};
    #pragma unroll
    for (int q = 0; q < 4; ++q) {
      float xl = (vv[q] - mu)*rs*gc[q] + bc[q];
      xsum_acc[q] += xl;
      short hv = f2bf(xl);
      xln[row + lane + 64*q] = hv;
      int c = lane + 64*q;
      ldsT[c*72 + (jl ^ (((c >> 3) & 7) << 3))] = hv;
    }
  }
  #pragma unroll
  for (int q = 0; q < 4; ++q) xsred[w][lane + 64*q] = xsum_acc[q];
  __syncthreads();
  xsum64[(((size_t)b*64 + jt) << 8) + t] =
      xsred[0][t] + xsred[1][t] + xsred[2][t] + xsred[3][t];
  #pragma unroll
  for (int it = 0; it < 8; ++it) {
    int cr = it*32 + (t >> 3);
    int j0 = (t & 7)*8;
    s16x8 v = *(const s16x8*)(ldsT + cr*72 + (j0 ^ (((cr >> 3) & 7) << 3)));
    *(s16x8*)(xlnT + (((size_t)b*256 + cr) << 12) + jt*64 + j0) = v;
  }
}

// ---------------------------------------------------------------------------
__global__ __launch_bounds__(256) void xsum_final(
    const float* __restrict__ xsum_part, int nch, float* __restrict__ xsumF)
{
  int b = blockIdx.x, t = threadIdx.x;
  float s = 0.f;
  for (int ch = 0; ch < nch; ++ch) s += xsum_part[(((size_t)b*nch + ch) << 8) + t];
  xsumF[b*256 + t] = s;
}

// ---------------------------------------------------------------------------
// attn2: grid 512 = (b, chunk of 256 j), 256 thr, 4 steps of 64 j.
// ---------------------------------------------------------------------------
#define A2_XS   0
#define A2_XT   (64*264*2)
#define A2_PS   (A2_XT + 256*72*2)
#define A2_PSUM (A2_PS + 32*72*2)
#define A2_QB   (A2_PSUM + 128*4)
#define A2_BYTES (A2_QB + 32*4)   // 75904

__global__ __launch_bounds__(256, 2) void attn2_kernel(
    const short* __restrict__ xln, const short* __restrict__ xlnT,
    const short* __restrict__ qk, const float* __restrict__ qb,
    float* __restrict__ A_part, float* __restrict__ psum_part)
{
  extern __shared__ char smem[];
  short* xs       = (short*)(smem + A2_XS);
  short* xt       = (short*)(smem + A2_XT);
  short* ps       = (short*)(smem + A2_PS);
  float* psum_lds = (float*)(smem + A2_PSUM);
  float* qb_lds   = (float*)(smem + A2_QB);

  int tid = threadIdx.x;
  int w = tid >> 6, lane = tid & 63;
  int g = lane >> 4, lj = lane & 15;
  int b = blockIdx.x >> 4, chunk = blockIdx.x & 15;
  int xr3 = (lj & 3) << 3;

  if (tid < 32) qb_lds[tid] = qb[b*R32 + tid];

  s16x8 qkf[2][8];
  #pragma unroll
  for (int mt = 0; mt < 2; ++mt)
    #pragma unroll
    for (int ks = 0; ks < 8; ++ks)
      qkf[mt][ks] = *(const s16x8*)(qk + ((size_t)(b*R32 + mt*16 + lj) << 8) + ks*32 + g*8);
  __syncthreads();

  float qb0[4], qb1[4];
  #pragma unroll
  for (int r = 0; r < 4; ++r) { qb0[r] = qb_lds[4*g + r]; qb1[r] = qb_lds[16 + 4*g + r]; }

  f32x4 zero4 = {0.f, 0.f, 0.f, 0.f};
  f32x4 accD[2][4];
  #pragma unroll
  for (int mt = 0; mt < 2; ++mt)
    #pragma unroll
    for (int nt = 0; nt < 4; ++nt) accD[mt][nt] = zero4;
  float psum_acc[8] = {0.f,0.f,0.f,0.f,0.f,0.f,0.f,0.f};

  for (int step = 0; step < 4; ++step) {
    int jbase = chunk*256 + step*64;
    const short* xrow = xln + (((size_t)b*SEQN + jbase) << 8);
    #pragma unroll
    for (int grp = 0; grp < 2; ++grp) {
      int tr = w*16 + (grp*2 + (lane >> 5))*4;
      int c0 = (lane & 31)*8;
      s16x8 rv[4];
      #pragma unroll
      for (int k = 0; k < 4; ++k) rv[k] = *(const s16x8*)(xrow + ((size_t)(tr + k) << 8) + c0);
      #pragma unroll
      for (int k = 0; k < 4; ++k)
        *(s16x8*)(xs + (tr + k)*264 + (c0 ^ (k << 3))) = rv[k];
    }
    const short* xtr = xlnT + (((size_t)b*256) << 12) + jbase;
    #pragma unroll
    for (int it = 0; it < 8; ++it) {
      int cr = w*64 + it*8 + (lane >> 3);
      int j0 = (lane & 7)*8;
      s16x8 v = *(const s16x8*)(xtr + ((size_t)cr << 12) + j0);
      *(s16x8*)(xt + cr*72 + (j0 ^ ((cr & 3) << 3))) = v;
    }
    f32x4 d0 = zero4, d1 = zero4;
    #pragma unroll
    for (int ks = 0; ks < 8; ++ks) {
      s16x8 bx = *(const s16x8*)(xs + (w*16 + lj)*264 + ((ks*32 + g*8) ^ xr3));
      d0 = __builtin_amdgcn_mfma_f32_16x16x32_bf16(qkf[0][ks], bx, d0, 0, 0, 0);
      d1 = __builtin_amdgcn_mfma_f32_16x16x32_bf16(qkf[1][ks], bx, d1, 0, 0, 0);
    }
    {
      float m0 = -1e30f;
      #pragma unroll
      for (int r = 0; r < 4; ++r) {
        m0 = fmaxf(m0, d0[r] + qb0[r]);
        m0 = fmaxf(m0, d1[r] + qb1[r]);
      }
      m0 = fmaxf(m0, __shfl_xor(m0, 16));
      m0 = fmaxf(m0, __shfl_xor(m0, 32));
      float e0[4], e1[4], ssum = 0.f;
      #pragma unroll
      for (int r = 0; r < 4; ++r) {
        e0[r] = __expf(d0[r] + qb0[r] - m0);
        e1[r] = __expf(d1[r] + qb1[r] - m0);
        ssum += e0[r] + e1[r];
      }
      ssum += __shfl_xor(ssum, 16);
      ssum += __shfl_xor(ssum, 32);
      float inv = 1.f/ssum;
      int jl = w*16 + lj;
      #pragma unroll
      for (int r = 0; r < 4; ++r) {
        float sm0 = e0[r]*inv, sm1 = e1[r]*inv;
        psum_acc[r]     += sm0;
        psum_acc[4 + r] += sm1;
        int jx = jl ^ (r << 3);
        ps[(4*g + r)*72 + jx]      = f2bf(sm0);
        ps[(16 + 4*g + r)*72 + jx] = f2bf(sm1);
      }
    }
    __syncthreads();
    #pragma unroll
    for (int ks = 0; ks < 2; ++ks) {
      int kx = (ks*32 + g*8) ^ xr3;
      s16x8 pa0 = *(const s16x8*)(ps + lj*72 + kx);
      s16x8 pa1 = *(const s16x8*)(ps + (16 + lj)*72 + kx);
      #pragma unroll
      for (int nt = 0; nt < 4; ++nt) {
        s16x8 bxt = *(const s16x8*)(xt + (w*64 + nt*16 + lj)*72 + kx);
        accD[0][nt] = __builtin_amdgcn_mfma_f32_16x16x32_bf16(pa0, bxt, accD[0][nt], 0, 0, 0);
        accD[1][nt] = __builtin_amdgcn_mfma_f32_16x16x32_bf16(pa1, bxt, accD[1][nt], 0, 0, 0);
      }
    }
    __syncthreads();
  }

  {
    float* ap = A_part + ((size_t)(b*16 + chunk) << 13);
    #pragma unroll
    for (int mt = 0; mt < 2; ++mt)
      #pragma unroll
      for (int nt = 0; nt < 4; ++nt)
        #pragma unroll
        for (int r = 0; r < 4; ++r)
          ap[(mt*16 + 4*g + r)*256 + w*64 + nt*16 + lj] = accD[mt][nt][r];
  }
  #pragma unroll
  for (int r = 0; r < 8; ++r)
    #pragma unroll
    for (int m = 1; m < 16; m <<= 1) psum_acc[r] += __shfl_xor(psum_acc[r], m);
  if (lj == 0) {
    #pragma unroll
    for (int r = 0; r < 4; ++r) {
      psum_lds[w*32 + 4*g + r]      = psum_acc[r];
      psum_lds[w*32 + 16 + 4*g + r] = psum_acc[4 + r];
    }
  }
  __syncthreads();
  if (tid < 32) {
    float sv = psum_lds[tid] + psum_lds[32+tid] + psum_lds[64+tid] + psum_lds[96+tid];
    psum_part[(b*16 + chunk)*32 + tid] = sv;
  }
}

// ---------------------------------------------------------------------------
// attn (fallback, LN inline) — proven round-1 kernel, unchanged.
// ---------------------------------------------------------------------------
#define XSTR 264
#define TSTR 72
#define PSTR 72
#define OFF_XT   (64*XSTR*2)
#define OFF_PS   (OFF_XT + 256*TSTR*2)
#define OFF_PSUM (OFF_PS + 32*PSTR*2)
#define OFF_XSUM (OFF_PSUM + 4*32*4)
#define OFF_QB   (OFF_XSUM + 4*256*4)
#define SMEM_BYTES (OFF_QB + 32*4)   // 80000

__global__ __launch_bounds__(256, 2) void attn_kernel(
    const float* __restrict__ inp,
    const float* __restrict__ ln_f_g, const float* __restrict__ ln_f_b,
    const short* __restrict__ qk, const float* __restrict__ qb,
    float* __restrict__ A_part, float* __restrict__ psum_part,
    float* __restrict__ xsum_part, int write_xsum)
{
  extern __shared__ char smem[];
  short* xs       = (short*)smem;
  short* xt       = (short*)(smem + OFF_XT);
  short* ps       = (short*)(smem + OFF_PS);
  float* psum_lds = (float*)(smem + OFF_PSUM);
  float* xsum_lds = (float*)(smem + OFF_XSUM);
  float* qb_lds   = (float*)(smem + OFF_QB);

  int tid = threadIdx.x;
  int w = tid >> 6, lane = tid & 63;
  int g = lane >> 4, lj = lane & 15;
  int b = blockIdx.x >> 4, chunk = blockIdx.x & 15;

  float gc[4], bc[4];
  #pragma unroll
  for (int q = 0; q < 4; ++q) { gc[q] = ln_f_g[lane + 64*q]; bc[q] = ln_f_b[lane + 64*q]; }

  if (tid < 32) qb_lds[tid] = qb[b*R32 + tid];

  s16x8 qkf[2][8];
  #pragma unroll
  for (int mt = 0; mt < 2; ++mt)
    #pragma unroll
    for (int ks = 0; ks < 8; ++ks)
      qkf[mt][ks] = *(const s16x8*)(qk + ((size_t)(b*R32 + mt*16 + lj) << 8) + ks*32 + g*8);
  __syncthreads();

  float qb0[4], qb1[4];
  #pragma unroll
  for (int r = 0; r < 4; ++r) { qb0[r] = qb_lds[4*g + r]; qb1[r] = qb_lds[16 + 4*g + r]; }

  f32x4 zero4 = {0.f, 0.f, 0.f, 0.f};
  f32x4 accD[2][4];
  #pragma unroll
  for (int mt = 0; mt < 2; ++mt)
    #pragma unroll
    for (int nt = 0; nt < 4; ++nt) accD[mt][nt] = zero4;
  float psum_acc[8] = {0.f,0.f,0.f,0.f,0.f,0.f,0.f,0.f};
  float xsum_acc[4] = {0.f,0.f,0.f,0.f};

  for (int step = 0; step < 4; ++step) {
    int jbase = chunk*256 + step*64;
    const float* rowp = inp + (((size_t)b*SEQN + jbase + w*16) << 8);
    short tq[4][4];
    #pragma unroll
    for (int rr = 0; rr < 16; ++rr) {
      const float* rp = rowp + ((size_t)rr << 8);
      float v0 = rp[lane], v1 = rp[lane+64], v2 = rp[lane+128], v3 = rp[lane+192];
      float s  = v0 + v1 + v2 + v3;
      float s2 = v0*v0 + v1*v1 + v2*v2 + v3*v3;
      #pragma unroll
      for (int m = 1; m < 64; m <<= 1) { s += __shfl_xor(s, m); s2 += __shfl_xor(s2, m); }
      float mu = s*(1.f/256.f);
      float var = s2*(1.f/256.f) - mu*mu;
      float rs = 1.f/sqrtf(var + LNEPS);
      int jrow = w*16 + rr;
      float vv[4] = {v0, v1, v2, v3};
      #pragma unroll
      for (int q = 0; q < 4; ++q) {
        float xl = (vv[q] - mu)*rs*gc[q] + bc[q];
        xsum_acc[q] += xl;
        short hv = f2bf(xl);
        xs[jrow*XSTR + lane + 64*q] = hv;
        tq[q][rr & 3] = hv;
      }
      if ((rr & 3) == 3) {
        #pragma unroll
        for (int q = 0; q < 4; ++q) {
          s16x4 pk = { tq[q][0], tq[q][1], tq[q][2], tq[q][3] };
          *(s16x4*)(xt + (lane + 64*q)*TSTR + w*16 + (rr - 3)) = pk;
        }
      }
    }
    f32x4 d0 = zero4, d1 = zero4;
    #pragma unroll
    for (int ks = 0; ks < 8; ++ks) {
      s16x8 bx = *(const s16x8*)(xs + (w*16 + lj)*XSTR + ks*32 + g*8);
      d0 = __builtin_amdgcn_mfma_f32_16x16x32_bf16(qkf[0][ks], bx, d0, 0, 0, 0);
      d1 = __builtin_amdgcn_mfma_f32_16x16x32_bf16(qkf[1][ks], bx, d1, 0, 0, 0);
    }
    {
      float m0 = -1e30f;
      #pragma unroll
      for (int r = 0; r < 4; ++r) {
        m0 = fmaxf(m0, d0[r] + qb0[r]);
        m0 = fmaxf(m0, d1[r] + qb1[r]);
      }
      m0 = fmaxf(m0, __shfl_xor(m0, 16));
      m0 = fmaxf(m0, __shfl_xor(m0, 32));
      float e0[4], e1[4], ssum = 0.f;
      #pragma unroll
      for (int r = 0; r < 4; ++r) {
        e0[r] = __expf(d0[r] + qb0[r] - m0);
        e1[r] = __expf(d1[r] + qb1[r] - m0);
        ssum += e0[r] + e1[r];
      }
      ssum += __shfl_xor(ssum, 16);
      ssum += __shfl_xor(ssum, 32);
      float inv = 1.f/ssum;
      int jl = w*16 + lj;
      #pragma unroll
      for (int r = 0; r < 4; ++r) {
        float sm0 = e0[r]*inv, sm1 = e1[r]*inv;
        psum_acc[r]     += sm0;
        psum_acc[4 + r] += sm1;
        ps[(4*g + r)*PSTR + jl]      = f2bf(sm0);
        ps[(16 + 4*g + r)*PSTR + jl] = f2bf(sm1);
      }
    }
    __syncthreads();
    #pragma unroll
    for (int ks = 0; ks < 2; ++ks) {
      s16x8 pa0 = *(const s16x8*)(ps + lj*PSTR + ks*32 + g*8);
      s16x8 pa1 = *(const s16x8*)(ps + (16 + lj)*PSTR + ks*32 + g*8);
      #pragma unroll
      for (int nt = 0; nt < 4; ++nt) {
        s16x8 bxt = *(const s16x8*)(xt + (w*64 + nt*16 + lj)*TSTR + ks*32 + g*8);
        accD[0][nt] = __builtin_amdgcn_mfma_f32_16x16x32_bf16(pa0, bxt, accD[0][nt], 0, 0, 0);
        accD[1][nt] = __builtin_amdgcn_mfma_f32_16x16x32_bf16(pa1, bxt, accD[1][nt], 0, 0, 0);
      }
    }
    __syncthreads();
  }

  {
    float* ap = A_part + ((size_t)(b*16 + chunk) << 13);
    #pragma unroll
    for (int mt = 0; mt < 2; ++mt)
      #pragma unroll
      for (int nt = 0; nt < 4; ++nt)
        #pragma unroll
        for (int r = 0; r < 4; ++r)
          ap[(mt*16 + 4*g + r)*256 + w*64 + nt*16 + lj] = accD[mt][nt][r];
  }
  #pragma unroll
  for (int r = 0; r < 8; ++r)
    #pragma unroll
    for (int m = 1; m < 16; m <<= 1) psum_acc[r] += __shfl_xor(psum_acc[r], m);
  if (lj == 0) {
    #pragma unroll
    for (int r = 0; r < 4; ++r) {
      psum_lds[w*32 + 4*g + r]      = psum_acc[r];
      psum_lds[w*32 + 16 + 4*g + r] = psum_acc[4 + r];
    }
  }
  #pragma unroll
  for (int q = 0; q < 4; ++q) xsum_lds[w*256 + lane + 64*q] = xsum_acc[q];
  __syncthreads();
  if (tid < 32) {
    float sv = psum_lds[tid] + psum_lds[32+tid] + psum_lds[64+tid] + psum_lds[96+tid];
    psum_part[(b*16 + chunk)*32 + tid] = sv;
  }
  if (write_xsum) {
    float sv = xsum_lds[tid] + xsum_lds[256+tid] + xsum_lds[512+tid] + xsum_lds[768+tid];
    xsum_part[((b*16 + chunk) << 8) + tid] = sv;
  }
}

// ---------------------------------------------------------------------------
// s3m: grid 32 (one per batch), 512 thr = 8 waves. M=8 slot rows (pad to 16).
// Every matvec is an MFMA GEMM: A = LDS bf16 activations [16][K] (rows 8..15
// zero), B = row-major bf16 weights [n][k] streamed 16B/lane from global.
// Fragment conventions identical to attn2 (bench-verified).
// ---------------------------------------------------------------------------
#define M3_AFH 0                    // bf16 [4][16][264]
#define M3_CAT 33792                // bf16 [16][520]  ([uu | hp])
#define M3_LNS 50432                // bf16 [16][264]
#define M3_HH  58880                // bf16 [16][520]
#define M3_QV  75520                // bf16 [16][264]
#define M3_RZ  83968                // f32 [8][512]
#define M3_INN 100352               // f32 [8][256]
#define M3_HNN 108544               // f32 [8][256]
#define M3_UHP 116736               // f32 [8][256] (hp)
#define M3_SNL 124928               // f32 [8][256]
#define M3_QVF 133120               // f32 [8][256]
#define M3_SR  141312               // f32 [32]
#define M3_BYTES 141440

__global__ __launch_bounds__(512, 1) void s3m_update(
    const float* __restrict__ A_part, const float* __restrict__ psum_part,
    const float* __restrict__ xsumF,
    const short* __restrict__ WvT,  const short* __restrict__ Wgru,
    const short* __restrict__ WihNN, const short* __restrict__ WhhNN,
    const short* __restrict__ W1T,  const short* __restrict__ W2T,
    const short* __restrict__ WqT,  const short* __restrict__ WkB,
    const float* __restrict__ bv,   const float* __restrict__ b_ih,
    const float* __restrict__ b_hh,
    const float* __restrict__ ln_ff_g, const float* __restrict__ ln_ff_b,
    const float* __restrict__ b1,   const float* __restrict__ b2,
    const float* __restrict__ ln_s_g, const float* __restrict__ ln_s_b,
    const float* __restrict__ bq,   const float* __restrict__ bk,
    float* __restrict__ slots_cur, short* __restrict__ qk,
    float* __restrict__ qb, float* __restrict__ out)
{
  extern __shared__ char sm[];
  short* afh  = (short*)(sm + M3_AFH);
  short* cat  = (short*)(sm + M3_CAT);
  short* lns  = (short*)(sm + M3_LNS);
  short* hhb  = (short*)(sm + M3_HH);
  short* qvb  = (short*)(sm + M3_QV);
  float* rz   = (float*)(sm + M3_RZ);
  float* innf = (float*)(sm + M3_INN);
  float* hnnf = (float*)(sm + M3_HNN);
  float* uhp  = (float*)(sm + M3_UHP);
  float* snl  = (float*)(sm + M3_SNL);
  float* qvf  = (float*)(sm + M3_QVF);
  float* srl  = (float*)(sm + M3_SR);

  int bb = blockIdx.x;
  int t = threadIdx.x;
  int w = t >> 6, lane = t & 63, g = lane >> 4, lj = lane & 15;
  f32x4 zero4 = {0.f, 0.f, 0.f, 0.f};

  // ---- phase 0: zero bf16 A-buffers; Sr ----
  for (int i = t; i < 20992; i += 512) ((int*)sm)[i] = 0;
  if (t < 32) {
    float p = 0.f;
    #pragma unroll
    for (int ch = 0; ch < 16; ++ch) p += psum_part[(bb*16 + ch)*32 + t];
    srl[t] = p + 4096.f*EPSA;
  }
  __syncthreads();

  // ---- phase 0b: hp load; A-reduce -> afh ----
  for (int idx = t; idx < 2048; idx += 512) {
    int row = idx >> 8, c = idx & 255;
    float v = slots_cur[bb*2048 + idx];
    uhp[row*256 + c] = v;
    cat[row*520 + 256 + c] = f2bf(v);
  }
  {
    int c = t & 255, rh = t >> 8;
    float xs = xsumF[bb*256 + c];
    #pragma unroll 1
    for (int k = 0; k < 16; ++k) {
      int r = rh*16 + k;
      float a = 0.f;
      #pragma unroll
      for (int ch = 0; ch < 16; ++ch)
        a += A_part[((size_t)((bb*16 + ch)*32 + r) << 8) + c];
      float val = (a + EPSA*xs) / srl[r];
      afh[((r & 3)*16 + (r >> 2))*264 + c] = f2bf(val);
    }
  }
  __syncthreads();

  // ---- stage 1: uu = Af_h @ WvT_h + bv  -> cat[:, 0..255] ----
  #pragma unroll
  for (int tt = w*2; tt < w*2 + 2; ++tt) {
    int h = tt >> 2, nt = tt & 3;
    int n = h*64 + nt*16 + lj;
    f32x4 acc = zero4;
    #pragma unroll
    for (int ks = 0; ks < 8; ++ks) {
      s16x8 a = *(const s16x8*)(afh + (h*16 + lj)*264 + ks*32 + g*8);
      s16x8 bfr = *(const s16x8*)(WvT + (size_t)n*256 + ks*32 + g*8);
      acc = __builtin_amdgcn_mfma_f32_16x16x32_bf16(a, bfr, acc, 0, 0, 0);
    }
    if (g < 2) {
      float bvn = bv[n];
      #pragma unroll
      for (int r = 0; r < 4; ++r) cat[(4*g + r)*520 + n] = f2bf(acc[r] + bvn);
    }
  }
  __syncthreads();

  // ---- stage 2: rz = [uu|hp] @ Wgru^T + b_ih + b_hh (N=512, K=512) ----
  #pragma unroll
  for (int tt = w*4; tt < w*4 + 4; ++tt) {
    int n = tt*16 + lj;
    f32x4 acc = zero4;
    #pragma unroll
    for (int ks = 0; ks < 16; ++ks) {
      s16x8 a = *(const s16x8*)(cat + lj*520 + ks*32 + g*8);
      s16x8 bfr = *(const s16x8*)(Wgru + (size_t)n*512 + ks*32 + g*8);
      acc = __builtin_amdgcn_mfma_f32_16x16x32_bf16(a, bfr, acc, 0, 0, 0);
    }
    if (g < 2) {
      float bbn = b_ih[n] + b_hh[n];
      #pragma unroll
      for (int r = 0; r < 4; ++r) rz[(4*g + r)*512 + n] = acc[r] + bbn;
    }
  }
  // ---- stage 3: inn = uu @ WihNN^T ; hnn = hp @ WhhNN^T (N=256, K=256) ----
  #pragma unroll
  for (int tt = w*2; tt < w*2 + 2; ++tt) {
    int n = tt*16 + lj;
    f32x4 ai = zero4, ah = zero4;
    #pragma unroll
    for (int ks = 0; ks < 8; ++ks) {
      s16x8 au = *(const s16x8*)(cat + lj*520 + ks*32 + g*8);
      s16x8 ap = *(const s16x8*)(cat + lj*520 + 256 + ks*32 + g*8);
      ai = __builtin_amdgcn_mfma_f32_16x16x32_bf16(au, *(const s16x8*)(WihNN + (size_t)n*256 + ks*32 + g*8), ai, 0, 0, 0);
      ah = __builtin_amdgcn_mfma_f32_16x16x32_bf16(ap, *(const s16x8*)(WhhNN + (size_t)n*256 + ks*32 + g*8), ah, 0, 0, 0);
    }
    if (g < 2) {
      float bi = b_ih[512 + n], bh = b_hh[512 + n];
      #pragma unroll
      for (int r = 0; r < 4; ++r) {
        innf[(4*g + r)*256 + n] = ai[r] + bi;
        hnnf[(4*g + r)*256 + n] = ah[r] + bh;
      }
    }
  }
  __syncthreads();

  // ---- stage 4: gates -> snl ; LN_ff -> lns ----
  #pragma unroll
  for (int rep = 0; rep < 4; ++rep) {
    int idx = t + rep*512;
    int row = idx >> 8, c = idx & 255;
    float rg = 1.f/(1.f + __expf(-rz[row*512 + c]));
    float zg = 1.f/(1.f + __expf(-rz[row*512 + 256 + c]));
    float ng = tanhf(innf[row*256 + c] + rg*hnnf[row*256 + c]);
    snl[row*256 + c] = (1.f - zg)*ng + zg*uhp[row*256 + c];
  }
  __syncthreads();
  {
    int row = w;
    float s1 = 0.f, s2 = 0.f;
    f32x4 v4 = *(const f32x4*)(snl + row*256 + lane*4);
    #pragma unroll
    for (int k = 0; k < 4; ++k) { s1 += v4[k]; s2 += v4[k]*v4[k]; }
    #pragma unroll
    for (int m = 1; m < 64; m <<= 1) { s1 += __shfl_xor(s1, m); s2 += __shfl_xor(s2, m); }
    float mu = s1*(1.f/256.f), var = s2*(1.f/256.f) - mu*mu;
    float rs = 1.f/sqrtf(var + LNEPS);
    s16x4 o;
    #pragma unroll
    for (int k = 0; k < 4; ++k) {
      int c = lane*4 + k;
      o[k] = f2bf((v4[k] - mu)*rs*ln_ff_g[c] + ln_ff_b[c]);
    }
    *(s16x4*)(lns + row*264 + lane*4) = o;
  }
  __syncthreads();

  // ---- stage 5: hh = relu(lns @ W1T^T + b1) (N=512, K=256) ----
  #pragma unroll
  for (int tt = w*4; tt < w*4 + 4; ++tt) {
    int n = tt*16 + lj;
    f32x4 acc = zero4;
    #pragma unroll
    for (int ks = 0; ks < 8; ++ks) {
      s16x8 a = *(const s16x8*)(lns + lj*264 + ks*32 + g*8);
      s16x8 bfr = *(const s16x8*)(W1T + (size_t)n*256 + ks*32 + g*8);
      acc = __builtin_amdgcn_mfma_f32_16x16x32_bf16(a, bfr, acc, 0, 0, 0);
    }
    if (g < 2) {
      float b1n = b1[n];
      #pragma unroll
      for (int r = 0; r < 4; ++r) hhb[(4*g + r)*520 + n] = f2bf(fmaxf(acc[r] + b1n, 0.f));
    }
  }
  __syncthreads();

  // ---- stage 6: sfin = snl + hh @ W2T^T + b2 (N=256, K=512) ; LN_s ----
  #pragma unroll
  for (int tt = w*2; tt < w*2 + 2; ++tt) {
    int n = tt*16 + lj;
    f32x4 acc = zero4;
    #pragma unroll
    for (int ks = 0; ks < 16; ++ks) {
      s16x8 a = *(const s16x8*)(hhb + lj*520 + ks*32 + g*8);
      s16x8 bfr = *(const s16x8*)(W2T + (size_t)n*512 + ks*32 + g*8);
      acc = __builtin_amdgcn_mfma_f32_16x16x32_bf16(a, bfr, acc, 0, 0, 0);
    }
    if (g < 2) {
      float b2n = b2[n];
      #pragma unroll
      for (int r = 0; r < 4; ++r) {
        int row = 4*g + r;
        float sfin = snl[row*256 + n] + acc[r] + b2n;
        snl[row*256 + n] = sfin;
        out[(bb*8 + row)*256 + n] = sfin;
        slots_cur[(bb*8 + row)*256 + n] = sfin;
      }
    }
  }
  __syncthreads();
  {
    int row = w;
    float s1 = 0.f, s2 = 0.f;
    f32x4 v4 = *(const f32x4*)(snl + row*256 + lane*4);
    #pragma unroll
    for (int k = 0; k < 4; ++k) { s1 += v4[k]; s2 += v4[k]*v4[k]; }
    #pragma unroll
    for (int m = 1; m < 64; m <<= 1) { s1 += __shfl_xor(s1, m); s2 += __shfl_xor(s2, m); }
    float mu = s1*(1.f/256.f), var = s2*(1.f/256.f) - mu*mu;
    float rs = 1.f/sqrtf(var + LNEPS);
    s16x4 o;
    #pragma unroll
    for (int k = 0; k < 4; ++k) {
      int c = lane*4 + k;
      o[k] = f2bf((v4[k] - mu)*rs*ln_s_g[c] + ln_s_b[c]);
    }
    *(s16x4*)(lns + row*264 + lane*4) = o;
  }
  __syncthreads();

  // ---- stage 7: qv = lns @ WqT^T + bq (N=256, K=256) ----
  #pragma unroll
  for (int tt = w*2; tt < w*2 + 2; ++tt) {
    int n = tt*16 + lj;
    f32x4 acc = zero4;
    #pragma unroll
    for (int ks = 0; ks < 8; ++ks) {
      s16x8 a = *(const s16x8*)(lns + lj*264 + ks*32 + g*8);
      s16x8 bfr = *(const s16x8*)(WqT + (size_t)n*256 + ks*32 + g*8);
      acc = __builtin_amdgcn_mfma_f32_16x16x32_bf16(a, bfr, acc, 0, 0, 0);
    }
    if (g < 2) {
      float bqn = bq[n];
      #pragma unroll
      for (int r = 0; r < 4; ++r) {
        int row = 4*g + r;
        float v = acc[r] + bqn;
        qvf[row*256 + n] = v;
        qvb[row*264 + n] = f2bf(v);
      }
    }
  }
  __syncthreads();

  // ---- stage 8: qk~ = SCALE * qv_h @ Wk_h^T (per head, N=256, K=64); qb ----
  #pragma unroll
  for (int job = w*8; job < w*8 + 8; ++job) {
    int h = job >> 4, nt = job & 15;
    int cc = nt*16 + lj;
    f32x4 acc = zero4;
    #pragma unroll
    for (int ks = 0; ks < 2; ++ks) {
      s16x8 a = *(const s16x8*)(qvb + lj*264 + h*64 + ks*32 + g*8);
      s16x8 bfr = *(const s16x8*)(WkB + (size_t)cc*256 + h*64 + ks*32 + g*8);
      acc = __builtin_amdgcn_mfma_f32_16x16x32_bf16(a, bfr, acc, 0, 0, 0);
    }
    if (g < 2) {
      #pragma unroll
      for (int r = 0; r < 4; ++r) {
        int row = 4*g + r;
        qk[((size_t)(bb*R32 + row*4 + h)) * 256 + cc] = f2bf(SCALE_F*acc[r]);
      }
    }
  }
  if (t < 256) {
    int si = t >> 5, h = (t >> 3) & 3, dg = t & 7;
    float pv = 0.f;
    #pragma unroll
    for (int d = 0; d < 8; ++d) pv += qvf[si*256 + h*64 + dg*8 + d]*bk[h*64 + dg*8 + d];
    pv += __shfl_xor(pv, 1); pv += __shfl_xor(pv, 2); pv += __shfl_xor(pv, 4);
    if (dg == 0) qb[bb*R32 + si*4 + h] = SCALE_F*pv;
  }
}

// ---------------------------------------------------------------------------
extern "C" void kernel_launch(void* const* d_in, const int* in_sizes, int n_in,
                              void* d_out, int out_size, void* d_ws, size_t ws_size,
                              hipStream_t stream) {
  (void)in_sizes; (void)n_in; (void)out_size;
  const float* inp        = (const float*)d_in[0];
  const float* slots_init = (const float*)d_in[1];
  const float* ln_f_g = (const float*)d_in[2];
  const float* ln_f_b = (const float*)d_in[3];
  const float* ln_s_g = (const float*)d_in[4];
  const float* ln_s_b = (const float*)d_in[5];
  const float* ln_ff_g = (const float*)d_in[6];
  const float* ln_ff_b = (const float*)d_in[7];
  const float* Wq = (const float*)d_in[8];
  const float* bq = (const float*)d_in[9];
  const float* Wk = (const float*)d_in[10];
  const float* bk = (const float*)d_in[11];
  const float* Wv = (const float*)d_in[12];
  const float* bv = (const float*)d_in[13];
  const float* W_ih = (const float*)d_in[14];
  const float* b_ih = (const float*)d_in[15];
  const float* W_hh = (const float*)d_in[16];
  const float* b_hh = (const float*)d_in[17];
  const float* W1 = (const float*)d_in[18];
  const float* b1 = (const float*)d_in[19];
  const float* W2 = (const float*)d_in[20];
  const float* b2 = (const float*)d_in[21];
  float* out = (float*)d_out;

  const size_t NEED_BIG = 155684864ULL;
  bool big = ws_size >= NEED_BIG;
  int nchx = big ? 64 : 16;

  char* ws = (char*)d_ws;
  size_t o = 0;
  auto alloc = [&](size_t bytes) { size_t r = o; o += (bytes + 255) & ~(size_t)255; return r; };
  float* A_part    = (float*)(ws + alloc(16777216));
  float* psum_part = (float*)(ws + alloc(65536));
  float* xsum_part = (float*)(ws + alloc(big ? 2097152 : 524288));
  short* qk        = (short*)(ws + alloc(524288));
  float* qbuf      = (float*)(ws + alloc(4096));
  float* slots_cur = (float*)(ws + alloc(262144));
  float* xsumF     = (float*)(ws + alloc(32768));
  short* WvT       = (short*)(ws + alloc(131072));
  short* W1T       = (short*)(ws + alloc(262144));
  short* W2T       = (short*)(ws + alloc(262144));
  short* WqT       = (short*)(ws + alloc(131072));
  short* Wgru      = (short*)(ws + alloc(524288));
  short* WihNN     = (short*)(ws + alloc(131072));
  short* WhhNN     = (short*)(ws + alloc(131072));
  short* WkB       = (short*)(ws + alloc(131072));
  short* xln  = nullptr;
  short* xlnT = nullptr;
  if (big) {
    xln  = (short*)(ws + alloc(67108864));
    xlnT = (short*)(ws + alloc(67108864));
  }

  hipFuncSetAttribute((const void*)attn_kernel,
                      hipFuncAttributeMaxDynamicSharedMemorySize, SMEM_BYTES);
  hipFuncSetAttribute((const void*)attn2_kernel,
                      hipFuncAttributeMaxDynamicSharedMemorySize, A2_BYTES);
  hipFuncSetAttribute((const void*)s3m_update,
                      hipFuncAttributeMaxDynamicSharedMemorySize, M3_BYTES);

  w_prep2<<<448, 256, 0, stream>>>(W_ih, W_hh, Wk, Wgru, WihNN, WhhNN, WkB);
  w_trans<<<96, 256, 0, stream>>>(Wv, W1, W2, Wq, WvT, W1T, W2T, WqT);
  s0_prep<<<256, 256, 0, stream>>>(slots_init, ln_s_g, ln_s_b, Wq, bq, Wk, bk,
                                   slots_cur, qk, qbuf);
  if (big) {
    xln_prep<<<2048, 256, 0, stream>>>(inp, ln_f_g, ln_f_b, xln, xlnT, xsum_part);
    xsum_final<<<32, 256, 0, stream>>>(xsum_part, nchx, xsumF);
  }
  for (int it = 0; it < 5; ++it) {
    if (big) {
      attn2_kernel<<<512, 256, A2_BYTES, stream>>>(xln, xlnT, qk, qbuf,
                                                   A_part, psum_part);
    } else {
      attn_kernel<<<512, 256, SMEM_BYTES, stream>>>(inp, ln_f_g, ln_f_b, qk, qbuf,
                                                    A_part, psum_part, xsum_part,
                                                    it == 0 ? 1 : 0);
      if (it == 0) xsum_final<<<32, 256, 0, stream>>>(xsum_part, nchx, xsumF);
    }
    s3m_update<<<32, 512, M3_BYTES, stream>>>(A_part, psum_part, xsumF,
                                              WvT, Wgru, WihNN, WhhNN,
                                              W1T, W2T, WqT, WkB,
                                              bv, b_ih, b_hh, ln_ff_g, ln_ff_b,
                                              b1, b2, ln_s_g, ln_s_b, bq, bk,
                                              slots_cur, qk, qbuf, out);
  }
}